// Round 1
// baseline (747.675 us; speedup 1.0000x reference)
//
#include <hip/hip_runtime.h>

#define N_NODES 50000
#define N_EDGES 800000
#define EA (N_EDGES + N_NODES)   // 850000 edges incl. self-loops
#define IN_CH 512
#define D1 256
#define HID 32
#define HEADS 8
#define NCLS 40
#define NEG 0.2f

// ---------------- CSR build (by dst) ----------------
__global__ void k_hist(const int* __restrict__ ei, int* __restrict__ deg) {
  int e = blockIdx.x * blockDim.x + threadIdx.x;
  if (e >= EA) return;
  int dst = (e < N_EDGES) ? ei[N_EDGES + e] : (e - N_EDGES);
  atomicAdd(&deg[dst], 1);
}

__global__ void k_scan_partial(const int* __restrict__ deg, int* __restrict__ partial) {
  __shared__ int s[512];
  int i = blockIdx.x * 512 + threadIdx.x;
  s[threadIdx.x] = (i < N_NODES) ? deg[i] : 0;
  __syncthreads();
  for (int off = 256; off > 0; off >>= 1) {
    if (threadIdx.x < off) s[threadIdx.x] += s[threadIdx.x + off];
    __syncthreads();
  }
  if (threadIdx.x == 0) partial[blockIdx.x] = s[0];
}

__global__ void k_scan_top(int* partial, int nb) {
  if (threadIdx.x || blockIdx.x) return;
  int acc = 0;
  for (int i = 0; i < nb; ++i) { int v = partial[i]; partial[i] = acc; acc += v; }
}

__global__ void k_scan_final(const int* __restrict__ deg, const int* __restrict__ partial,
                             int* __restrict__ rowptr, int* __restrict__ wofs) {
  __shared__ int s[512];
  int t = threadIdx.x, i = blockIdx.x * 512 + t;
  int v = (i < N_NODES) ? deg[i] : 0;
  s[t] = v;
  __syncthreads();
  for (int off = 1; off < 512; off <<= 1) {   // Hillis-Steele inclusive scan
    int u = (t >= off) ? s[t - off] : 0;
    __syncthreads();
    s[t] += u;
    __syncthreads();
  }
  if (i < N_NODES) {
    int excl = partial[blockIdx.x] + s[t] - v;
    rowptr[i] = excl;
    wofs[i]   = excl;
    if (i == N_NODES - 1) rowptr[N_NODES] = excl + v;
  }
}

__global__ void k_scatter(const int* __restrict__ ei, int* __restrict__ wofs,
                          int* __restrict__ csr_src, int* __restrict__ csr_dst) {
  int e = blockIdx.x * blockDim.x + threadIdx.x;
  if (e >= EA) return;
  int src, dst;
  if (e < N_EDGES) { src = ei[e]; dst = ei[N_EDGES + e]; }
  else             { src = e - N_EDGES; dst = src; }
  int pos = atomicAdd(&wofs[dst], 1);
  csr_src[pos] = src;
  csr_dst[pos] = dst;
}

// ---------------- GEMM1: h1[M,256] = x[M,512] @ W1[512,256], fp32 ----------------
// 128x64 tile, 256 threads, 8x4 microtile, K-step 16.
__global__ __launch_bounds__(256) void k_gemm1(const float* __restrict__ A,
                                               const float* __restrict__ B,
                                               float* __restrict__ C) {
  __shared__ float As[16][128];
  __shared__ float Bs[16][64];
  const int M = N_NODES, K = IN_CH, Nn = D1;
  int bm = blockIdx.x * 128, bn = blockIdx.y * 64;
  int t = threadIdx.x;
  int tx = t & 15, ty = t >> 4;
  int lrow = t >> 1, lkq = (t & 1) * 8;
  float acc[8][4] = {};
  for (int k0 = 0; k0 < K; k0 += 16) {
    float4 a0 = make_float4(0.f,0.f,0.f,0.f), a1 = make_float4(0.f,0.f,0.f,0.f);
    if (bm + lrow < M) {
      const float* ap = &A[(size_t)(bm + lrow) * K + k0 + lkq];
      a0 = *(const float4*)ap;
      a1 = *(const float4*)(ap + 4);
    }
    As[lkq+0][lrow]=a0.x; As[lkq+1][lrow]=a0.y; As[lkq+2][lrow]=a0.z; As[lkq+3][lrow]=a0.w;
    As[lkq+4][lrow]=a1.x; As[lkq+5][lrow]=a1.y; As[lkq+6][lrow]=a1.z; As[lkq+7][lrow]=a1.w;
    int bk = t >> 4, bnn = (t & 15) * 4;
    *(float4*)&Bs[bk][bnn] = *(const float4*)&B[(size_t)(k0 + bk) * Nn + bn + bnn];
    __syncthreads();
    #pragma unroll
    for (int k = 0; k < 16; ++k) {
      float4 av0 = *(const float4*)&As[k][ty*8];
      float4 av1 = *(const float4*)&As[k][ty*8+4];
      float4 bv  = *(const float4*)&Bs[k][tx*4];
      float a[8] = {av0.x,av0.y,av0.z,av0.w,av1.x,av1.y,av1.z,av1.w};
      float b[4] = {bv.x,bv.y,bv.z,bv.w};
      #pragma unroll
      for (int i = 0; i < 8; ++i)
        #pragma unroll
        for (int j = 0; j < 4; ++j)
          acc[i][j] += a[i] * b[j];
    }
    __syncthreads();
  }
  #pragma unroll
  for (int i = 0; i < 8; ++i) {
    int row = bm + ty*8 + i;
    if (row < M)
      *(float4*)&C[(size_t)row * Nn + bn + tx*4] =
          make_float4(acc[i][0], acc[i][1], acc[i][2], acc[i][3]);
  }
}

// ---------------- attention logits per node, layer 1 (wave per node) ----------------
__global__ __launch_bounds__(256) void k_al1(const float* __restrict__ h1,
                                             const float* __restrict__ att_s,
                                             const float* __restrict__ att_d,
                                             float* __restrict__ al_s,
                                             float* __restrict__ al_d) {
  int node = (blockIdx.x * 256 + threadIdx.x) >> 6;
  int lane = threadIdx.x & 63;
  if (node >= N_NODES) return;
  float4 hv = *(const float4*)&h1[(size_t)node * 256 + lane * 4];
  float4 as = *(const float4*)&att_s[lane * 4];
  float4 ad = *(const float4*)&att_d[lane * 4];
  float ps = hv.x*as.x + hv.y*as.y + hv.z*as.z + hv.w*as.w;
  float pd = hv.x*ad.x + hv.y*ad.y + hv.z*ad.z + hv.w*ad.w;
  for (int s = 1; s < 8; s <<= 1) {   // reduce the 8 lanes of each head group
    ps += __shfl_xor(ps, s, 64);
    pd += __shfl_xor(pd, s, 64);
  }
  if ((lane & 7) == 0) {
    al_s[node * 8 + (lane >> 3)] = ps;
    al_d[node * 8 + (lane >> 3)] = pd;
  }
}

// ---------------- edge scores e1[pos][h], CSR order ----------------
__global__ void k_e1(const int* __restrict__ csr_src, const int* __restrict__ csr_dst,
                     const float* __restrict__ al_s, const float* __restrict__ al_d,
                     float* __restrict__ e1) {
  int i = blockIdx.x * blockDim.x + threadIdx.x;
  if (i >= EA * 8) return;
  int pos = i >> 3, h = i & 7;
  float v = al_s[csr_src[pos] * 8 + h] + al_d[csr_dst[pos] * 8 + h];
  e1[i] = (v > 0.f) ? v : NEG * v;
}

// ---------------- layer-1 softmax-aggregate + bias + ELU (wave per dst node) ----------------
__global__ __launch_bounds__(256) void k_agg1(const int* __restrict__ rowptr,
                                              const int* __restrict__ csr_src,
                                              const float* __restrict__ e1,
                                              const float* __restrict__ h1,
                                              const float* __restrict__ b1,
                                              float* __restrict__ x2) {
  int node = (blockIdx.x * 256 + threadIdx.x) >> 6;
  int lane = threadIdx.x & 63;
  if (node >= N_NODES) return;
  int start = rowptr[node], end = rowptr[node + 1];
  int h = lane & 7, g = lane >> 3;
  // phase 1: per-head max (lanes: 8 heads x 8 edge strides, coalesced e1 reads)
  float mx = -1e30f;
  for (int idx = start + g; idx < end; idx += 8)
    mx = fmaxf(mx, e1[idx * 8 + h]);
  for (int s = 8; s < 64; s <<= 1)
    mx = fmaxf(mx, __shfl_xor(mx, s, 64));
  // phase 2: per-head sum of exp
  float dsum = 0.f;
  for (int idx = start + g; idx < end; idx += 8)
    dsum += __expf(e1[idx * 8 + h] - mx);
  for (int s = 8; s < 64; s <<= 1)
    dsum += __shfl_xor(dsum, s, 64);
  float inv = 1.f / (dsum + 1e-16f);
  // phase 3: lane owns channels 4*lane..+3 (head = lane>>3); gather h1[src] rows
  int h3 = lane >> 3;
  float mx3  = __shfl(mx, h3, 64);
  float inv3 = __shfl(inv, h3, 64);
  float4 acc = make_float4(0.f,0.f,0.f,0.f);
  for (int idx = start; idx < end; ++idx) {
    int src = csr_src[idx];
    float al = __expf(e1[idx * 8 + h3] - mx3) * inv3;
    float4 hv = *(const float4*)&h1[(size_t)src * 256 + lane * 4];
    acc.x += al * hv.x; acc.y += al * hv.y; acc.z += al * hv.z; acc.w += al * hv.w;
  }
  float4 bb = *(const float4*)&b1[lane * 4];
  float4 o;
  float vx = acc.x + bb.x; o.x = vx > 0.f ? vx : __expf(vx) - 1.f;
  float vy = acc.y + bb.y; o.y = vy > 0.f ? vy : __expf(vy) - 1.f;
  float vz = acc.z + bb.z; o.z = vz > 0.f ? vz : __expf(vz) - 1.f;
  float vw = acc.w + bb.w; o.w = vw > 0.f ? vw : __expf(vw) - 1.f;
  *(float4*)&x2[(size_t)node * 256 + lane * 4] = o;
}

// ---------------- GEMM2: h2[M,40] = x2[M,256] @ W2[256,40] ----------------
__global__ __launch_bounds__(320) void k_gemm2(const float* __restrict__ x2,
                                               const float* __restrict__ W2,
                                               float* __restrict__ h2) {
  __shared__ float Ws[D1 * NCLS];   // 40 KB
  int t = threadIdx.x;
  for (int i = t; i < D1 * NCLS; i += 320) Ws[i] = W2[i];
  __syncthreads();
  int r = blockIdx.x * 8 + t / NCLS;
  int c = t % NCLS;
  if (r >= N_NODES) return;
  float acc = 0.f;
  const float* xr = &x2[(size_t)r * D1];
  for (int k = 0; k < D1; k += 4) {
    float4 xv = *(const float4*)&xr[k];
    acc += xv.x * Ws[(k+0)*NCLS + c] + xv.y * Ws[(k+1)*NCLS + c]
         + xv.z * Ws[(k+2)*NCLS + c] + xv.w * Ws[(k+3)*NCLS + c];
  }
  h2[(size_t)r * NCLS + c] = acc;
}

__global__ void k_al2(const float* __restrict__ h2, const float* __restrict__ att_s,
                      const float* __restrict__ att_d,
                      float* __restrict__ al_s, float* __restrict__ al_d) {
  int n = blockIdx.x * blockDim.x + threadIdx.x;
  if (n >= N_NODES) return;
  float ps = 0.f, pd = 0.f;
  const float* hr = &h2[(size_t)n * NCLS];
  for (int c = 0; c < NCLS; ++c) { float v = hr[c]; ps += v * att_s[c]; pd += v * att_d[c]; }
  al_s[n] = ps; al_d[n] = pd;
}

__global__ void k_e2(const int* __restrict__ csr_src, const int* __restrict__ csr_dst,
                     const float* __restrict__ al_s, const float* __restrict__ al_d,
                     float* __restrict__ e2) {
  int pos = blockIdx.x * blockDim.x + threadIdx.x;
  if (pos >= EA) return;
  float v = al_s[csr_src[pos]] + al_d[csr_dst[pos]];
  e2[pos] = (v > 0.f) ? v : NEG * v;
}

// ---------------- layer-2 softmax-aggregate + bias (wave per dst node) ----------------
__global__ __launch_bounds__(256) void k_agg2(const int* __restrict__ rowptr,
                                              const int* __restrict__ csr_src,
                                              const float* __restrict__ e2,
                                              const float* __restrict__ h2,
                                              const float* __restrict__ b2,
                                              float* __restrict__ out) {
  int node = (blockIdx.x * 256 + threadIdx.x) >> 6;
  int lane = threadIdx.x & 63;
  if (node >= N_NODES) return;
  int start = rowptr[node], end = rowptr[node + 1];
  float mx = -1e30f;
  for (int idx = start + lane; idx < end; idx += 64)
    mx = fmaxf(mx, e2[idx]);
  for (int s = 1; s < 64; s <<= 1)
    mx = fmaxf(mx, __shfl_xor(mx, s, 64));
  float dsum = 0.f;
  for (int idx = start + lane; idx < end; idx += 64)
    dsum += __expf(e2[idx] - mx);
  for (int s = 1; s < 64; s <<= 1)
    dsum += __shfl_xor(dsum, s, 64);
  float inv = 1.f / (dsum + 1e-16f);
  float acc = 0.f;
  for (int idx = start; idx < end; ++idx) {
    float al = __expf(e2[idx] - mx) * inv;
    if (lane < NCLS) acc += al * h2[(size_t)csr_src[idx] * NCLS + lane];
  }
  if (lane < NCLS) out[(size_t)node * NCLS + lane] = acc + b2[lane];
}

extern "C" void kernel_launch(void* const* d_in, const int* in_sizes, int n_in,
                              void* d_out, int out_size, void* d_ws, size_t ws_size,
                              hipStream_t stream) {
  const float* x   = (const float*)d_in[0];
  const int*   ei  = (const int*)d_in[1];
  const float* W1  = (const float*)d_in[2];
  const float* as1 = (const float*)d_in[3];
  const float* ad1 = (const float*)d_in[4];
  const float* b1  = (const float*)d_in[5];
  const float* W2  = (const float*)d_in[6];
  const float* as2 = (const float*)d_in[7];
  const float* ad2 = (const float*)d_in[8];
  const float* b2  = (const float*)d_in[9];
  float* out = (float*)d_out;

  // workspace carve-up (~152 MB total)
  char* p = (char*)d_ws;
  auto alloc = [&](size_t bytes) { char* r = p; p += (bytes + 15) & ~size_t(15); return r; };
  float* h1    = (float*)alloc((size_t)N_NODES * 256 * 4);
  float* x2    = (float*)alloc((size_t)N_NODES * 256 * 4);
  float* e1    = (float*)alloc((size_t)EA * 8 * 4);
  float* h2    = (float*)alloc((size_t)N_NODES * NCLS * 4);
  float* al_s1 = (float*)alloc((size_t)N_NODES * 8 * 4);
  float* al_d1 = (float*)alloc((size_t)N_NODES * 8 * 4);
  float* al_s2 = (float*)alloc((size_t)N_NODES * 4);
  float* al_d2 = (float*)alloc((size_t)N_NODES * 4);
  float* e2    = (float*)alloc((size_t)EA * 4);
  int* deg     = (int*)alloc((size_t)N_NODES * 4);
  int* rowptr  = (int*)alloc((size_t)(N_NODES + 1) * 4);
  int* wofs    = (int*)alloc((size_t)N_NODES * 4);
  int* partial = (int*)alloc(128 * 4);
  int* csr_src = (int*)alloc((size_t)EA * 4);
  int* csr_dst = (int*)alloc((size_t)EA * 4);

  const int NB = (N_NODES + 511) / 512;  // 98

  hipMemsetAsync(deg, 0, (size_t)N_NODES * 4, stream);
  k_hist<<<(EA + 255) / 256, 256, 0, stream>>>(ei, deg);
  k_scan_partial<<<NB, 512, 0, stream>>>(deg, partial);
  k_scan_top<<<1, 64, 0, stream>>>(partial, NB);
  k_scan_final<<<NB, 512, 0, stream>>>(deg, partial, rowptr, wofs);
  k_scatter<<<(EA + 255) / 256, 256, 0, stream>>>(ei, wofs, csr_src, csr_dst);

  dim3 g1((N_NODES + 127) / 128, 4);
  k_gemm1<<<g1, 256, 0, stream>>>(x, W1, h1);
  k_al1<<<(N_NODES + 3) / 4, 256, 0, stream>>>(h1, as1, ad1, al_s1, al_d1);
  k_e1<<<(EA * 8 + 255) / 256, 256, 0, stream>>>(csr_src, csr_dst, al_s1, al_d1, e1);
  k_agg1<<<(N_NODES + 3) / 4, 256, 0, stream>>>(rowptr, csr_src, e1, h1, b1, x2);

  k_gemm2<<<(N_NODES + 7) / 8, 320, 0, stream>>>(x2, W2, h2);
  k_al2<<<(N_NODES + 255) / 256, 256, 0, stream>>>(h2, as2, ad2, al_s2, al_d2);
  k_e2<<<(EA + 255) / 256, 256, 0, stream>>>(csr_src, csr_dst, al_s2, al_d2, e2);
  k_agg2<<<(N_NODES + 3) / 4, 256, 0, stream>>>(rowptr, csr_src, e2, h2, b2, out);
}

// Round 2
// 639.632 us; speedup vs baseline: 1.1689x; 1.1689x over previous
//
#include <hip/hip_runtime.h>

#define N_NODES 50000
#define N_EDGES 800000
#define EA (N_EDGES + N_NODES)   // 850000 edges incl. self-loops
#define IN_CH 512
#define D1 256
#define HID 32
#define HEADS 8
#define NCLS 40
#define NEG 0.2f

typedef unsigned short u16;
typedef unsigned int u32;
typedef __attribute__((ext_vector_type(8))) short bf16x8;
typedef __attribute__((ext_vector_type(4))) float f32x4;

__device__ inline u16 f2bf(float f) {           // round-to-nearest-even fp32->bf16
  u32 u = __float_as_uint(f);
  u += 0x7FFFu + ((u >> 16) & 1u);
  return (u16)(u >> 16);
}
__device__ inline u32 pack2(float a, float b) {
  return (u32)f2bf(a) | ((u32)f2bf(b) << 16);
}

// ---------------- CSR build (by dst) ----------------
__global__ void k_hist(const int* __restrict__ ei, int* __restrict__ deg) {
  int e = blockIdx.x * blockDim.x + threadIdx.x;
  if (e >= EA) return;
  int dst = (e < N_EDGES) ? ei[N_EDGES + e] : (e - N_EDGES);
  atomicAdd(&deg[dst], 1);
}

__global__ void k_scan_partial(const int* __restrict__ deg, int* __restrict__ partial) {
  __shared__ int s[512];
  int i = blockIdx.x * 512 + threadIdx.x;
  s[threadIdx.x] = (i < N_NODES) ? deg[i] : 0;
  __syncthreads();
  for (int off = 256; off > 0; off >>= 1) {
    if (threadIdx.x < off) s[threadIdx.x] += s[threadIdx.x + off];
    __syncthreads();
  }
  if (threadIdx.x == 0) partial[blockIdx.x] = s[0];
}

__global__ void k_scan_top(int* partial, int nb) {
  if (threadIdx.x || blockIdx.x) return;
  int acc = 0;
  for (int i = 0; i < nb; ++i) { int v = partial[i]; partial[i] = acc; acc += v; }
}

__global__ void k_scan_final(const int* __restrict__ deg, const int* __restrict__ partial,
                             int* __restrict__ rowptr, int* __restrict__ wofs) {
  __shared__ int s[512];
  int t = threadIdx.x, i = blockIdx.x * 512 + t;
  int v = (i < N_NODES) ? deg[i] : 0;
  s[t] = v;
  __syncthreads();
  for (int off = 1; off < 512; off <<= 1) {   // Hillis-Steele inclusive scan
    int u = (t >= off) ? s[t - off] : 0;
    __syncthreads();
    s[t] += u;
    __syncthreads();
  }
  if (i < N_NODES) {
    int excl = partial[blockIdx.x] + s[t] - v;
    rowptr[i] = excl;
    wofs[i]   = excl;
    if (i == N_NODES - 1) rowptr[N_NODES] = excl + v;
  }
}

__global__ void k_scatter(const int* __restrict__ ei, int* __restrict__ wofs,
                          int* __restrict__ csr_src, int* __restrict__ csr_dst) {
  int e = blockIdx.x * blockDim.x + threadIdx.x;
  if (e >= EA) return;
  int src, dst;
  if (e < N_EDGES) { src = ei[e]; dst = ei[N_EDGES + e]; }
  else             { src = e - N_EDGES; dst = src; }
  int pos = atomicAdd(&wofs[dst], 1);
  csr_src[pos] = src;
  csr_dst[pos] = dst;
}

// ---------------- casts: x -> bf16 (row-major), W1 -> bf16 transposed [256][512] ----------------
__global__ __launch_bounds__(256) void k_cast_x(const float* __restrict__ x, u32* __restrict__ xb) {
  size_t i = (size_t)blockIdx.x * 256 + threadIdx.x;   // one thread = 8 floats
  if (i >= (size_t)N_NODES * IN_CH / 8) return;
  const float4* src = (const float4*)(x + i * 8);
  float4 v0 = src[0], v1 = src[1];
  uint4 o;
  o.x = pack2(v0.x, v0.y); o.y = pack2(v0.z, v0.w);
  o.z = pack2(v1.x, v1.y); o.w = pack2(v1.z, v1.w);
  ((uint4*)xb)[i] = o;
}

__global__ __launch_bounds__(256) void k_cast_w1t(const float* __restrict__ W1, u16* __restrict__ BT) {
  int id = blockIdx.x * 256 + threadIdx.x;   // id = n*512 + k
  if (id >= D1 * IN_CH) return;
  int n = id >> 9, k = id & 511;
  BT[id] = f2bf(W1[(size_t)k * D1 + n]);
}

// ---------------- GEMM1 (bf16 MFMA): h1[M,256] = xb[M,512] @ W1T^T ----------------
// 128x128 tile, BK=32, 256 threads (4 waves), each wave a 64x64 subtile via 4x4 of 16x16x32 MFMA.
__global__ __launch_bounds__(256) void k_gemm1_mfma(const u16* __restrict__ A,   // [M,512] bf16
                                                    const u16* __restrict__ BT,  // [256,512] bf16
                                                    float* __restrict__ C) {     // [M,256] fp32
  __shared__ u16 As[128 * 32];   // 8 KB
  __shared__ u16 Bs[128 * 32];   // 8 KB
  const int M = N_NODES;
  int bm = blockIdx.x * 128;
  int bn = blockIdx.y * 128;
  int t = threadIdx.x;
  int lane = t & 63, wave = t >> 6;
  int wm = (wave & 1) * 64, wn = (wave >> 1) * 64;

  // staging: per global_load_lds issue, wave covers 16 rows (4 lanes/row, 16B/lane)
  int ldrow = wave * 16 + (lane >> 2);      // 0..63 within an issue-pass
  int ldk   = (lane & 3) * 8;               // 0,8,16,24
  int arow0 = bm + ldrow;       if (arow0 >= M) arow0 = M - 1;
  int arow1 = bm + 64 + ldrow;  if (arow1 >= M) arow1 = M - 1;
  int brow0 = bn + ldrow;
  int brow1 = bn + 64 + ldrow;
  // wave-uniform LDS bases (HW writes lane i at base + i*16B)
  u16* asd0 = &As[(wave * 16) * 32];
  u16* asd1 = &As[(64 + wave * 16) * 32];
  u16* bsd0 = &Bs[(wave * 16) * 32];
  u16* bsd1 = &Bs[(64 + wave * 16) * 32];

  int am = wm + (lane & 15);                // A frag row (local)
  int bnn = wn + (lane & 15);               // B frag col (local)
  int kq = (lane >> 4) * 8;                 // frag k offset within BK

  f32x4 acc[4][4] = {};

  for (int k0 = 0; k0 < IN_CH; k0 += 32) {
    __builtin_amdgcn_global_load_lds(
        (const __attribute__((address_space(1))) void*)&A[(size_t)arow0 * IN_CH + k0 + ldk],
        (__attribute__((address_space(3))) void*)asd0, 16, 0, 0);
    __builtin_amdgcn_global_load_lds(
        (const __attribute__((address_space(1))) void*)&A[(size_t)arow1 * IN_CH + k0 + ldk],
        (__attribute__((address_space(3))) void*)asd1, 16, 0, 0);
    __builtin_amdgcn_global_load_lds(
        (const __attribute__((address_space(1))) void*)&BT[(size_t)brow0 * IN_CH + k0 + ldk],
        (__attribute__((address_space(3))) void*)bsd0, 16, 0, 0);
    __builtin_amdgcn_global_load_lds(
        (const __attribute__((address_space(1))) void*)&BT[(size_t)brow1 * IN_CH + k0 + ldk],
        (__attribute__((address_space(3))) void*)bsd1, 16, 0, 0);
    __syncthreads();

    bf16x8 af[4], bfr[4];
    #pragma unroll
    for (int i = 0; i < 4; ++i)
      af[i] = *(const bf16x8*)&As[(am + i * 16) * 32 + kq];
    #pragma unroll
    for (int j = 0; j < 4; ++j)
      bfr[j] = *(const bf16x8*)&Bs[(bnn + j * 16) * 32 + kq];
    #pragma unroll
    for (int i = 0; i < 4; ++i)
      #pragma unroll
      for (int j = 0; j < 4; ++j)
        acc[i][j] = __builtin_amdgcn_mfma_f32_16x16x32_bf16(af[i], bfr[j], acc[i][j], 0, 0, 0);
    __syncthreads();
  }

  // epilogue: C/D layout col=lane&15, row=(lane>>4)*4+r
  #pragma unroll
  for (int i = 0; i < 4; ++i) {
    #pragma unroll
    for (int j = 0; j < 4; ++j) {
      int col = bn + wn + j * 16 + (lane & 15);
      int rowb = bm + wm + i * 16 + (lane >> 4) * 4;
      #pragma unroll
      for (int r = 0; r < 4; ++r) {
        int row = rowb + r;
        if (row < M) C[(size_t)row * D1 + col] = acc[i][j][r];
      }
    }
  }
}

// ---------------- attention logits per node, layer 1 (wave per node) ----------------
__global__ __launch_bounds__(256) void k_al1(const float* __restrict__ h1,
                                             const float* __restrict__ att_s,
                                             const float* __restrict__ att_d,
                                             float* __restrict__ al_s,
                                             float* __restrict__ al_d) {
  int node = (blockIdx.x * 256 + threadIdx.x) >> 6;
  int lane = threadIdx.x & 63;
  if (node >= N_NODES) return;
  float4 hv = *(const float4*)&h1[(size_t)node * 256 + lane * 4];
  float4 as = *(const float4*)&att_s[lane * 4];
  float4 ad = *(const float4*)&att_d[lane * 4];
  float ps = hv.x*as.x + hv.y*as.y + hv.z*as.z + hv.w*as.w;
  float pd = hv.x*ad.x + hv.y*ad.y + hv.z*ad.z + hv.w*ad.w;
  for (int s = 1; s < 8; s <<= 1) {   // reduce the 8 lanes of each head group
    ps += __shfl_xor(ps, s, 64);
    pd += __shfl_xor(pd, s, 64);
  }
  if ((lane & 7) == 0) {
    al_s[node * 8 + (lane >> 3)] = ps;
    al_d[node * 8 + (lane >> 3)] = pd;
  }
}

// ---------------- edge scores e1[pos][h], CSR order ----------------
__global__ void k_e1(const int* __restrict__ csr_src, const int* __restrict__ csr_dst,
                     const float* __restrict__ al_s, const float* __restrict__ al_d,
                     float* __restrict__ e1) {
  int i = blockIdx.x * blockDim.x + threadIdx.x;
  if (i >= EA * 8) return;
  int pos = i >> 3, h = i & 7;
  float v = al_s[csr_src[pos] * 8 + h] + al_d[csr_dst[pos] * 8 + h];
  e1[i] = (v > 0.f) ? v : NEG * v;
}

// ---------------- layer-1 softmax-aggregate + bias + ELU (wave per dst node) ----------------
__global__ __launch_bounds__(256) void k_agg1(const int* __restrict__ rowptr,
                                              const int* __restrict__ csr_src,
                                              const float* __restrict__ e1,
                                              const float* __restrict__ h1,
                                              const float* __restrict__ b1,
                                              float* __restrict__ x2) {
  int node = (blockIdx.x * 256 + threadIdx.x) >> 6;
  int lane = threadIdx.x & 63;
  if (node >= N_NODES) return;
  int start = rowptr[node], end = rowptr[node + 1];
  int h = lane & 7, g = lane >> 3;
  float mx = -1e30f;
  for (int idx = start + g; idx < end; idx += 8)
    mx = fmaxf(mx, e1[idx * 8 + h]);
  for (int s = 8; s < 64; s <<= 1)
    mx = fmaxf(mx, __shfl_xor(mx, s, 64));
  float dsum = 0.f;
  for (int idx = start + g; idx < end; idx += 8)
    dsum += __expf(e1[idx * 8 + h] - mx);
  for (int s = 8; s < 64; s <<= 1)
    dsum += __shfl_xor(dsum, s, 64);
  float inv = 1.f / (dsum + 1e-16f);
  int h3 = lane >> 3;
  float mx3  = __shfl(mx, h3, 64);
  float inv3 = __shfl(inv, h3, 64);
  float4 acc = make_float4(0.f,0.f,0.f,0.f);
  for (int idx = start; idx < end; ++idx) {
    int src = csr_src[idx];
    float al = __expf(e1[idx * 8 + h3] - mx3) * inv3;
    float4 hv = *(const float4*)&h1[(size_t)src * 256 + lane * 4];
    acc.x += al * hv.x; acc.y += al * hv.y; acc.z += al * hv.z; acc.w += al * hv.w;
  }
  float4 bb = *(const float4*)&b1[lane * 4];
  float4 o;
  float vx = acc.x + bb.x; o.x = vx > 0.f ? vx : __expf(vx) - 1.f;
  float vy = acc.y + bb.y; o.y = vy > 0.f ? vy : __expf(vy) - 1.f;
  float vz = acc.z + bb.z; o.z = vz > 0.f ? vz : __expf(vz) - 1.f;
  float vw = acc.w + bb.w; o.w = vw > 0.f ? vw : __expf(vw) - 1.f;
  *(float4*)&x2[(size_t)node * 256 + lane * 4] = o;
}

// ---------------- GEMM2: h2[M,40] = x2[M,256] @ W2[256,40] ----------------
__global__ __launch_bounds__(320) void k_gemm2(const float* __restrict__ x2,
                                               const float* __restrict__ W2,
                                               float* __restrict__ h2) {
  __shared__ float Ws[D1 * NCLS];   // 40 KB
  int t = threadIdx.x;
  for (int i = t; i < D1 * NCLS; i += 320) Ws[i] = W2[i];
  __syncthreads();
  int r = blockIdx.x * 8 + t / NCLS;
  int c = t % NCLS;
  if (r >= N_NODES) return;
  float acc = 0.f;
  const float* xr = &x2[(size_t)r * D1];
  for (int k = 0; k < D1; k += 4) {
    float4 xv = *(const float4*)&xr[k];
    acc += xv.x * Ws[(k+0)*NCLS + c] + xv.y * Ws[(k+1)*NCLS + c]
         + xv.z * Ws[(k+2)*NCLS + c] + xv.w * Ws[(k+3)*NCLS + c];
  }
  h2[(size_t)r * NCLS + c] = acc;
}

__global__ void k_al2(const float* __restrict__ h2, const float* __restrict__ att_s,
                      const float* __restrict__ att_d,
                      float* __restrict__ al_s, float* __restrict__ al_d) {
  int n = blockIdx.x * blockDim.x + threadIdx.x;
  if (n >= N_NODES) return;
  float ps = 0.f, pd = 0.f;
  const float* hr = &h2[(size_t)n * NCLS];
  for (int c = 0; c < NCLS; ++c) { float v = hr[c]; ps += v * att_s[c]; pd += v * att_d[c]; }
  al_s[n] = ps; al_d[n] = pd;
}

__global__ void k_e2(const int* __restrict__ csr_src, const int* __restrict__ csr_dst,
                     const float* __restrict__ al_s, const float* __restrict__ al_d,
                     float* __restrict__ e2) {
  int pos = blockIdx.x * blockDim.x + threadIdx.x;
  if (pos >= EA) return;
  float v = al_s[csr_src[pos]] + al_d[csr_dst[pos]];
  e2[pos] = (v > 0.f) ? v : NEG * v;
}

// ---------------- layer-2 softmax-aggregate + bias (wave per dst node) ----------------
__global__ __launch_bounds__(256) void k_agg2(const int* __restrict__ rowptr,
                                              const int* __restrict__ csr_src,
                                              const float* __restrict__ e2,
                                              const float* __restrict__ h2,
                                              const float* __restrict__ b2,
                                              float* __restrict__ out) {
  int node = (blockIdx.x * 256 + threadIdx.x) >> 6;
  int lane = threadIdx.x & 63;
  if (node >= N_NODES) return;
  int start = rowptr[node], end = rowptr[node + 1];
  float mx = -1e30f;
  for (int idx = start + lane; idx < end; idx += 64)
    mx = fmaxf(mx, e2[idx]);
  for (int s = 1; s < 64; s <<= 1)
    mx = fmaxf(mx, __shfl_xor(mx, s, 64));
  float dsum = 0.f;
  for (int idx = start + lane; idx < end; idx += 64)
    dsum += __expf(e2[idx] - mx);
  for (int s = 1; s < 64; s <<= 1)
    dsum += __shfl_xor(dsum, s, 64);
  float inv = 1.f / (dsum + 1e-16f);
  float acc = 0.f;
  for (int idx = start; idx < end; ++idx) {
    float al = __expf(e2[idx] - mx) * inv;
    if (lane < NCLS) acc += al * h2[(size_t)csr_src[idx] * NCLS + lane];
  }
  if (lane < NCLS) out[(size_t)node * NCLS + lane] = acc + b2[lane];
}

extern "C" void kernel_launch(void* const* d_in, const int* in_sizes, int n_in,
                              void* d_out, int out_size, void* d_ws, size_t ws_size,
                              hipStream_t stream) {
  const float* x   = (const float*)d_in[0];
  const int*   ei  = (const int*)d_in[1];
  const float* W1  = (const float*)d_in[2];
  const float* as1 = (const float*)d_in[3];
  const float* ad1 = (const float*)d_in[4];
  const float* b1  = (const float*)d_in[5];
  const float* W2  = (const float*)d_in[6];
  const float* as2 = (const float*)d_in[7];
  const float* ad2 = (const float*)d_in[8];
  const float* b2  = (const float*)d_in[9];
  float* out = (float*)d_out;

  // workspace carve-up
  char* p = (char*)d_ws;
  auto alloc = [&](size_t bytes) { char* r = p; p += (bytes + 15) & ~size_t(15); return r; };
  float* h1    = (float*)alloc((size_t)N_NODES * 256 * 4);
  float* x2    = (float*)alloc((size_t)N_NODES * 256 * 4);   // also aliased as xb (bf16 x) pre-agg1
  float* e1    = (float*)alloc((size_t)EA * 8 * 4);
  float* h2    = (float*)alloc((size_t)N_NODES * NCLS * 4);
  float* al_s1 = (float*)alloc((size_t)N_NODES * 8 * 4);
  float* al_d1 = (float*)alloc((size_t)N_NODES * 8 * 4);
  float* al_s2 = (float*)alloc((size_t)N_NODES * 4);
  float* al_d2 = (float*)alloc((size_t)N_NODES * 4);
  float* e2    = (float*)alloc((size_t)EA * 4);
  int* deg     = (int*)alloc((size_t)N_NODES * 4);
  int* rowptr  = (int*)alloc((size_t)(N_NODES + 1) * 4);
  int* wofs    = (int*)alloc((size_t)N_NODES * 4);
  int* partial = (int*)alloc(128 * 4);
  int* csr_src = (int*)alloc((size_t)EA * 4);
  int* csr_dst = (int*)alloc((size_t)EA * 4);
  u16* w1t     = (u16*)alloc((size_t)D1 * IN_CH * 2);

  // xb (bf16 x, 51.2 MB) aliases x2: dead before k_agg1 writes x2
  u16* xb = (u16*)x2;

  const int NB = (N_NODES + 511) / 512;  // 98

  hipMemsetAsync(deg, 0, (size_t)N_NODES * 4, stream);
  k_hist<<<(EA + 255) / 256, 256, 0, stream>>>(ei, deg);
  k_scan_partial<<<NB, 512, 0, stream>>>(deg, partial);
  k_scan_top<<<1, 64, 0, stream>>>(partial, NB);
  k_scan_final<<<NB, 512, 0, stream>>>(deg, partial, rowptr, wofs);
  k_scatter<<<(EA + 255) / 256, 256, 0, stream>>>(ei, wofs, csr_src, csr_dst);

  k_cast_x<<<(N_NODES * IN_CH / 8 + 255) / 256, 256, 0, stream>>>(x, (u32*)xb);
  k_cast_w1t<<<(D1 * IN_CH + 255) / 256, 256, 0, stream>>>(W1, w1t);

  dim3 g1((N_NODES + 127) / 128, 2);
  k_gemm1_mfma<<<g1, 256, 0, stream>>>(xb, w1t, h1);

  k_al1<<<(N_NODES + 3) / 4, 256, 0, stream>>>(h1, as1, ad1, al_s1, al_d1);
  k_e1<<<(EA * 8 + 255) / 256, 256, 0, stream>>>(csr_src, csr_dst, al_s1, al_d1, e1);
  k_agg1<<<(N_NODES + 3) / 4, 256, 0, stream>>>(rowptr, csr_src, e1, h1, b1, x2);

  k_gemm2<<<(N_NODES + 7) / 8, 320, 0, stream>>>(x2, W2, h2);
  k_al2<<<(N_NODES + 255) / 256, 256, 0, stream>>>(h2, as2, ad2, al_s2, al_d2);
  k_e2<<<(EA + 255) / 256, 256, 0, stream>>>(csr_src, csr_dst, al_s2, al_d2, e2);
  k_agg2<<<(N_NODES + 3) / 4, 256, 0, stream>>>(rowptr, csr_src, e2, h2, b2, out);
}

// Round 3
// 600.799 us; speedup vs baseline: 1.2445x; 1.0646x over previous
//
#include <hip/hip_runtime.h>

#define N_NODES 50000
#define N_EDGES 800000
#define EA (N_EDGES + N_NODES)   // 850000 edges incl. self-loops
#define IN_CH 512
#define D1 256
#define HID 32
#define HEADS 8
#define NCLS 40
#define NEG 0.2f

typedef unsigned short u16;
typedef unsigned int u32;
typedef __attribute__((ext_vector_type(8))) short bf16x8;
typedef __attribute__((ext_vector_type(4))) float f32x4;

__device__ inline u16 f2bf(float f) {           // round-to-nearest-even fp32->bf16
  u32 u = __float_as_uint(f);
  u += 0x7FFFu + ((u >> 16) & 1u);
  return (u16)(u >> 16);
}
__device__ inline u32 pack2(float a, float b) {
  return (u32)f2bf(a) | ((u32)f2bf(b) << 16);
}
__device__ inline float bflo(u32 v) { return __uint_as_float(v << 16); }
__device__ inline float bfhi(u32 v) { return __uint_as_float(v & 0xffff0000u); }

// ---------------- CSR build (by dst) ----------------
__global__ void k_hist(const int* __restrict__ ei, int* __restrict__ deg) {
  int e = blockIdx.x * blockDim.x + threadIdx.x;
  if (e >= EA) return;
  int dst = (e < N_EDGES) ? ei[N_EDGES + e] : (e - N_EDGES);
  atomicAdd(&deg[dst], 1);
}

__global__ void k_scan_partial(const int* __restrict__ deg, int* __restrict__ partial) {
  __shared__ int s[512];
  int i = blockIdx.x * 512 + threadIdx.x;
  s[threadIdx.x] = (i < N_NODES) ? deg[i] : 0;
  __syncthreads();
  for (int off = 256; off > 0; off >>= 1) {
    if (threadIdx.x < off) s[threadIdx.x] += s[threadIdx.x + off];
    __syncthreads();
  }
  if (threadIdx.x == 0) partial[blockIdx.x] = s[0];
}

__global__ void k_scan_top(int* partial, int nb) {
  if (threadIdx.x || blockIdx.x) return;
  int acc = 0;
  for (int i = 0; i < nb; ++i) { int v = partial[i]; partial[i] = acc; acc += v; }
}

__global__ void k_scan_final(const int* __restrict__ deg, const int* __restrict__ partial,
                             int* __restrict__ rowptr, int* __restrict__ wofs) {
  __shared__ int s[512];
  int t = threadIdx.x, i = blockIdx.x * 512 + t;
  int v = (i < N_NODES) ? deg[i] : 0;
  s[t] = v;
  __syncthreads();
  for (int off = 1; off < 512; off <<= 1) {   // Hillis-Steele inclusive scan
    int u = (t >= off) ? s[t - off] : 0;
    __syncthreads();
    s[t] += u;
    __syncthreads();
  }
  if (i < N_NODES) {
    int excl = partial[blockIdx.x] + s[t] - v;
    rowptr[i] = excl;
    wofs[i]   = excl;
    if (i == N_NODES - 1) rowptr[N_NODES] = excl + v;
  }
}

__global__ void k_scatter(const int* __restrict__ ei, int* __restrict__ wofs,
                          int* __restrict__ csr_src, int* __restrict__ csr_dst) {
  int e = blockIdx.x * blockDim.x + threadIdx.x;
  if (e >= EA) return;
  int src, dst;
  if (e < N_EDGES) { src = ei[e]; dst = ei[N_EDGES + e]; }
  else             { src = e - N_EDGES; dst = src; }
  int pos = atomicAdd(&wofs[dst], 1);
  csr_src[pos] = src;
  csr_dst[pos] = dst;
}

// ---------------- casts: x -> bf16 (row-major), W1 -> bf16 transposed [256][512] ----------------
__global__ __launch_bounds__(256) void k_cast_x(const float* __restrict__ x, u32* __restrict__ xb) {
  size_t i = (size_t)blockIdx.x * 256 + threadIdx.x;   // one thread = 8 floats
  if (i >= (size_t)N_NODES * IN_CH / 8) return;
  const float4* src = (const float4*)(x + i * 8);
  float4 v0 = src[0], v1 = src[1];
  uint4 o;
  o.x = pack2(v0.x, v0.y); o.y = pack2(v0.z, v0.w);
  o.z = pack2(v1.x, v1.y); o.w = pack2(v1.z, v1.w);
  ((uint4*)xb)[i] = o;
}

__global__ __launch_bounds__(256) void k_cast_w1t(const float* __restrict__ W1, u16* __restrict__ BT) {
  int id = blockIdx.x * 256 + threadIdx.x;   // id = n*512 + k
  if (id >= D1 * IN_CH) return;
  int n = id >> 9, k = id & 511;
  BT[id] = f2bf(W1[(size_t)k * D1 + n]);
}

// ---------------- GEMM1 (bf16 MFMA): h1b[M,256] (bf16) = xb[M,512] @ W1T^T ----------------
// 128x128 tile, BK=32, 256 threads (4 waves), each wave a 64x64 subtile via 4x4 of 16x16x32 MFMA.
__global__ __launch_bounds__(256) void k_gemm1_mfma(const u16* __restrict__ A,   // [M,512] bf16
                                                    const u16* __restrict__ BT,  // [256,512] bf16
                                                    u16* __restrict__ Cb) {      // [M,256] bf16
  __shared__ u16 As[128 * 32];   // 8 KB
  __shared__ u16 Bs[128 * 32];   // 8 KB
  const int M = N_NODES;
  int bm = blockIdx.x * 128;
  int bn = blockIdx.y * 128;
  int t = threadIdx.x;
  int lane = t & 63, wave = t >> 6;
  int wm = (wave & 1) * 64, wn = (wave >> 1) * 64;

  int ldrow = wave * 16 + (lane >> 2);
  int ldk   = (lane & 3) * 8;
  int arow0 = bm + ldrow;       if (arow0 >= M) arow0 = M - 1;
  int arow1 = bm + 64 + ldrow;  if (arow1 >= M) arow1 = M - 1;
  int brow0 = bn + ldrow;
  int brow1 = bn + 64 + ldrow;
  u16* asd0 = &As[(wave * 16) * 32];
  u16* asd1 = &As[(64 + wave * 16) * 32];
  u16* bsd0 = &Bs[(wave * 16) * 32];
  u16* bsd1 = &Bs[(64 + wave * 16) * 32];

  int am = wm + (lane & 15);
  int bnn = wn + (lane & 15);
  int kq = (lane >> 4) * 8;

  f32x4 acc[4][4] = {};

  for (int k0 = 0; k0 < IN_CH; k0 += 32) {
    __builtin_amdgcn_global_load_lds(
        (const __attribute__((address_space(1))) void*)&A[(size_t)arow0 * IN_CH + k0 + ldk],
        (__attribute__((address_space(3))) void*)asd0, 16, 0, 0);
    __builtin_amdgcn_global_load_lds(
        (const __attribute__((address_space(1))) void*)&A[(size_t)arow1 * IN_CH + k0 + ldk],
        (__attribute__((address_space(3))) void*)asd1, 16, 0, 0);
    __builtin_amdgcn_global_load_lds(
        (const __attribute__((address_space(1))) void*)&BT[(size_t)brow0 * IN_CH + k0 + ldk],
        (__attribute__((address_space(3))) void*)bsd0, 16, 0, 0);
    __builtin_amdgcn_global_load_lds(
        (const __attribute__((address_space(1))) void*)&BT[(size_t)brow1 * IN_CH + k0 + ldk],
        (__attribute__((address_space(3))) void*)bsd1, 16, 0, 0);
    __syncthreads();

    bf16x8 af[4], bfr[4];
    #pragma unroll
    for (int i = 0; i < 4; ++i)
      af[i] = *(const bf16x8*)&As[(am + i * 16) * 32 + kq];
    #pragma unroll
    for (int j = 0; j < 4; ++j)
      bfr[j] = *(const bf16x8*)&Bs[(bnn + j * 16) * 32 + kq];
    #pragma unroll
    for (int i = 0; i < 4; ++i)
      #pragma unroll
      for (int j = 0; j < 4; ++j)
        acc[i][j] = __builtin_amdgcn_mfma_f32_16x16x32_bf16(af[i], bfr[j], acc[i][j], 0, 0, 0);
    __syncthreads();
  }

  // epilogue: C/D layout col=lane&15, row=(lane>>4)*4+r ; store bf16
  #pragma unroll
  for (int i = 0; i < 4; ++i) {
    #pragma unroll
    for (int j = 0; j < 4; ++j) {
      int col = bn + wn + j * 16 + (lane & 15);
      int rowb = bm + wm + i * 16 + (lane >> 4) * 4;
      #pragma unroll
      for (int r = 0; r < 4; ++r) {
        int row = rowb + r;
        if (row < M) Cb[(size_t)row * D1 + col] = f2bf(acc[i][j][r]);
      }
    }
  }
}

// ---------------- attention logits per node, layer 1 (wave per node, bf16 h1) ----------------
__global__ __launch_bounds__(256) void k_al1(const u16* __restrict__ h1b,
                                             const float* __restrict__ att_s,
                                             const float* __restrict__ att_d,
                                             float* __restrict__ al_s,
                                             float* __restrict__ al_d) {
  int node = (blockIdx.x * 256 + threadIdx.x) >> 6;
  int lane = threadIdx.x & 63;
  if (node >= N_NODES) return;
  uint2 hv = *(const uint2*)&h1b[(size_t)node * 256 + lane * 4];
  float v0 = bflo(hv.x), v1 = bfhi(hv.x), v2 = bflo(hv.y), v3 = bfhi(hv.y);
  float4 as = *(const float4*)&att_s[lane * 4];
  float4 ad = *(const float4*)&att_d[lane * 4];
  float ps = v0*as.x + v1*as.y + v2*as.z + v3*as.w;
  float pd = v0*ad.x + v1*ad.y + v2*ad.z + v3*ad.w;
  for (int s = 1; s < 8; s <<= 1) {
    ps += __shfl_xor(ps, s, 64);
    pd += __shfl_xor(pd, s, 64);
  }
  if ((lane & 7) == 0) {
    al_s[node * 8 + (lane >> 3)] = ps;
    al_d[node * 8 + (lane >> 3)] = pd;
  }
}

// ---------------- layer-1 softmax-aggregate + bias + ELU (wave per dst node) ----------------
// on-the-fly logits (no e1 buffer), no max pass (logits bounded ~|4|), bf16 h1 gather
__global__ __launch_bounds__(256) void k_agg1(const int* __restrict__ rowptr,
                                              const int* __restrict__ csr_src,
                                              const float* __restrict__ al_s,
                                              const float* __restrict__ al_d,
                                              const u16* __restrict__ h1b,
                                              const float* __restrict__ b1,
                                              float* __restrict__ x2) {
  int node = (blockIdx.x * 256 + threadIdx.x) >> 6;
  int lane = threadIdx.x & 63;
  if (node >= N_NODES) return;
  int start = rowptr[node], end = rowptr[node + 1];
  int h = lane & 7, g = lane >> 3;
  float aldv = al_d[node * 8 + h];           // wave-uniform per head h
  // phase 1: per-head sum of exp (groups of 8 lanes stride edges; head h per lane)
  float dsum = 0.f;
  for (int idx = start + g; idx < end; idx += 8) {
    int src = csr_src[idx];                  // broadcast within group
    float e = al_s[src * 8 + h] + aldv;      // 32B contiguous per group
    e = (e > 0.f) ? e : NEG * e;
    dsum += __expf(e);
  }
  for (int s = 8; s < 64; s <<= 1)
    dsum += __shfl_xor(dsum, s, 64);
  float inv = 1.f / (dsum + 1e-16f);
  // phase 2: lane owns channels 4*lane..+3 (head h3 = lane>>3)
  int h3 = lane >> 3;
  float inv3  = __shfl(inv, h3, 64);
  float aldv3 = __shfl(aldv, h3, 64);
  float4 acc = make_float4(0.f, 0.f, 0.f, 0.f);
  for (int idx = start; idx < end; ++idx) {
    int src = csr_src[idx];                  // broadcast all lanes
    float e = al_s[src * 8 + h3] + aldv3;    // 8 distinct dwords (one 32B line)
    e = (e > 0.f) ? e : NEG * e;
    float p = __expf(e) * inv3;
    uint2 hv = *(const uint2*)&h1b[(size_t)src * 256 + lane * 4];  // 512B/row gather
    acc.x += p * bflo(hv.x);
    acc.y += p * bfhi(hv.x);
    acc.z += p * bflo(hv.y);
    acc.w += p * bfhi(hv.y);
  }
  float4 bb = *(const float4*)&b1[lane * 4];
  float4 o;
  float vx = acc.x + bb.x; o.x = vx > 0.f ? vx : __expf(vx) - 1.f;
  float vy = acc.y + bb.y; o.y = vy > 0.f ? vy : __expf(vy) - 1.f;
  float vz = acc.z + bb.z; o.z = vz > 0.f ? vz : __expf(vz) - 1.f;
  float vw = acc.w + bb.w; o.w = vw > 0.f ? vw : __expf(vw) - 1.f;
  *(float4*)&x2[(size_t)node * 256 + lane * 4] = o;
}

// ---------------- GEMM2: h2[M,40] = x2[M,256] @ W2[256,40] ----------------
__global__ __launch_bounds__(320) void k_gemm2(const float* __restrict__ x2,
                                               const float* __restrict__ W2,
                                               float* __restrict__ h2) {
  __shared__ float Ws[D1 * NCLS];   // 40 KB
  int t = threadIdx.x;
  for (int i = t; i < D1 * NCLS; i += 320) Ws[i] = W2[i];
  __syncthreads();
  int r = blockIdx.x * 8 + t / NCLS;
  int c = t % NCLS;
  if (r >= N_NODES) return;
  float acc = 0.f;
  const float* xr = &x2[(size_t)r * D1];
  for (int k = 0; k < D1; k += 4) {
    float4 xv = *(const float4*)&xr[k];
    acc += xv.x * Ws[(k+0)*NCLS + c] + xv.y * Ws[(k+1)*NCLS + c]
         + xv.z * Ws[(k+2)*NCLS + c] + xv.w * Ws[(k+3)*NCLS + c];
  }
  h2[(size_t)r * NCLS + c] = acc;
}

__global__ void k_al2(const float* __restrict__ h2, const float* __restrict__ att_s,
                      const float* __restrict__ att_d,
                      float* __restrict__ al_s, float* __restrict__ al_d) {
  int n = blockIdx.x * blockDim.x + threadIdx.x;
  if (n >= N_NODES) return;
  float ps = 0.f, pd = 0.f;
  const float* hr = &h2[(size_t)n * NCLS];
  for (int c = 0; c < NCLS; ++c) { float v = hr[c]; ps += v * att_s[c]; pd += v * att_d[c]; }
  al_s[n] = ps; al_d[n] = pd;
}

// ---------------- layer-2 softmax-aggregate + bias (wave per dst node) ----------------
// on-the-fly logits, no max pass
__global__ __launch_bounds__(256) void k_agg2(const int* __restrict__ rowptr,
                                              const int* __restrict__ csr_src,
                                              const float* __restrict__ al_s,
                                              const float* __restrict__ al_d,
                                              const float* __restrict__ h2,
                                              const float* __restrict__ b2,
                                              float* __restrict__ out) {
  int node = (blockIdx.x * 256 + threadIdx.x) >> 6;
  int lane = threadIdx.x & 63;
  if (node >= N_NODES) return;
  int start = rowptr[node], end = rowptr[node + 1];
  float aldv = al_d[node];
  float dsum = 0.f;
  for (int idx = start + lane; idx < end; idx += 64) {
    float e = al_s[csr_src[idx]] + aldv;     // 4B gather in 200KB table (L2-hit)
    e = (e > 0.f) ? e : NEG * e;
    dsum += __expf(e);
  }
  for (int s = 1; s < 64; s <<= 1)
    dsum += __shfl_xor(dsum, s, 64);
  float inv = 1.f / (dsum + 1e-16f);
  float acc = 0.f;
  for (int idx = start; idx < end; ++idx) {
    int src = csr_src[idx];                  // broadcast
    float e = al_s[src] + aldv;
    e = (e > 0.f) ? e : NEG * e;
    float p = __expf(e) * inv;
    if (lane < NCLS) acc += p * h2[(size_t)src * NCLS + lane];
  }
  if (lane < NCLS) out[(size_t)node * NCLS + lane] = acc + b2[lane];
}

extern "C" void kernel_launch(void* const* d_in, const int* in_sizes, int n_in,
                              void* d_out, int out_size, void* d_ws, size_t ws_size,
                              hipStream_t stream) {
  const float* x   = (const float*)d_in[0];
  const int*   ei  = (const int*)d_in[1];
  const float* W1  = (const float*)d_in[2];
  const float* as1 = (const float*)d_in[3];
  const float* ad1 = (const float*)d_in[4];
  const float* b1  = (const float*)d_in[5];
  const float* W2  = (const float*)d_in[6];
  const float* as2 = (const float*)d_in[7];
  const float* ad2 = (const float*)d_in[8];
  const float* b2  = (const float*)d_in[9];
  float* out = (float*)d_out;

  // workspace carve-up
  char* p = (char*)d_ws;
  auto alloc = [&](size_t bytes) { char* r = p; p += (bytes + 15) & ~size_t(15); return r; };
  u16*  h1b   = (u16*)alloc((size_t)N_NODES * D1 * 2);     // 25.6 MB bf16
  float* x2    = (float*)alloc((size_t)N_NODES * D1 * 4);  // 51.2 MB, aliased as xb pre-agg1
  float* h2    = (float*)alloc((size_t)N_NODES * NCLS * 4);
  float* al_s1 = (float*)alloc((size_t)N_NODES * 8 * 4);
  float* al_d1 = (float*)alloc((size_t)N_NODES * 8 * 4);
  float* al_s2 = (float*)alloc((size_t)N_NODES * 4);
  float* al_d2 = (float*)alloc((size_t)N_NODES * 4);
  int* deg     = (int*)alloc((size_t)N_NODES * 4);
  int* rowptr  = (int*)alloc((size_t)(N_NODES + 1) * 4);
  int* wofs    = (int*)alloc((size_t)N_NODES * 4);
  int* partial = (int*)alloc(128 * 4);
  int* csr_src = (int*)alloc((size_t)EA * 4);
  int* csr_dst = (int*)alloc((size_t)EA * 4);
  u16* w1t     = (u16*)alloc((size_t)D1 * IN_CH * 2);

  // xb (bf16 x, 51.2 MB) aliases x2: dead before k_agg1 writes x2
  u16* xb = (u16*)x2;

  const int NB = (N_NODES + 511) / 512;  // 98

  hipMemsetAsync(deg, 0, (size_t)N_NODES * 4, stream);
  k_hist<<<(EA + 255) / 256, 256, 0, stream>>>(ei, deg);
  k_scan_partial<<<NB, 512, 0, stream>>>(deg, partial);
  k_scan_top<<<1, 64, 0, stream>>>(partial, NB);
  k_scan_final<<<NB, 512, 0, stream>>>(deg, partial, rowptr, wofs);
  k_scatter<<<(EA + 255) / 256, 256, 0, stream>>>(ei, wofs, csr_src, csr_dst);

  k_cast_x<<<(N_NODES * IN_CH / 8 + 255) / 256, 256, 0, stream>>>(x, (u32*)xb);
  k_cast_w1t<<<(D1 * IN_CH + 255) / 256, 256, 0, stream>>>(W1, w1t);

  dim3 g1((N_NODES + 127) / 128, 2);
  k_gemm1_mfma<<<g1, 256, 0, stream>>>(xb, w1t, h1b);

  k_al1<<<(N_NODES + 3) / 4, 256, 0, stream>>>(h1b, as1, ad1, al_s1, al_d1);
  k_agg1<<<(N_NODES + 3) / 4, 256, 0, stream>>>(rowptr, csr_src, al_s1, al_d1, h1b, b1, x2);

  k_gemm2<<<(N_NODES + 7) / 8, 320, 0, stream>>>(x2, W2, h2);
  k_al2<<<(N_NODES + 255) / 256, 256, 0, stream>>>(h2, as2, ad2, al_s2, al_d2);
  k_agg2<<<(N_NODES + 3) / 4, 256, 0, stream>>>(rowptr, csr_src, al_s2, al_d2, h2, b2, out);
}

// Round 4
// 501.390 us; speedup vs baseline: 1.4912x; 1.1983x over previous
//
#include <hip/hip_runtime.h>

#define N_NODES 50000
#define N_EDGES 800000
#define EA (N_EDGES + N_NODES)   // 850000 edges incl. self-loops
#define IN_CH 512
#define D1 256
#define HID 32
#define HEADS 8
#define NCLS 40
#define NEG 0.2f

typedef unsigned short u16;
typedef unsigned int u32;
typedef __attribute__((ext_vector_type(8))) short bf16x8;
typedef __attribute__((ext_vector_type(4))) float f32x4;

__device__ inline u16 f2bf(float f) {           // round-to-nearest-even fp32->bf16
  u32 u = __float_as_uint(f);
  u += 0x7FFFu + ((u >> 16) & 1u);
  return (u16)(u >> 16);
}
__device__ inline u32 pack2(float a, float b) {
  return (u32)f2bf(a) | ((u32)f2bf(b) << 16);
}
__device__ inline float bflo(u32 v) { return __uint_as_float(v << 16); }
__device__ inline float bfhi(u32 v) { return __uint_as_float(v & 0xffff0000u); }

// ---------------- CSR build (by dst) ----------------
__global__ void k_hist(const int* __restrict__ ei, int* __restrict__ deg) {
  int e = blockIdx.x * blockDim.x + threadIdx.x;
  if (e >= EA) return;
  int dst = (e < N_EDGES) ? ei[N_EDGES + e] : (e - N_EDGES);
  atomicAdd(&deg[dst], 1);
}

__global__ void k_scan_partial(const int* __restrict__ deg, int* __restrict__ partial) {
  __shared__ int s[512];
  int i = blockIdx.x * 512 + threadIdx.x;
  s[threadIdx.x] = (i < N_NODES) ? deg[i] : 0;
  __syncthreads();
  for (int off = 256; off > 0; off >>= 1) {
    if (threadIdx.x < off) s[threadIdx.x] += s[threadIdx.x + off];
    __syncthreads();
  }
  if (threadIdx.x == 0) partial[blockIdx.x] = s[0];
}

__global__ void k_scan_top(int* partial, int nb) {
  if (threadIdx.x || blockIdx.x) return;
  int acc = 0;
  for (int i = 0; i < nb; ++i) { int v = partial[i]; partial[i] = acc; acc += v; }
}

__global__ void k_scan_final(const int* __restrict__ deg, const int* __restrict__ partial,
                             int* __restrict__ rowptr, int* __restrict__ wofs) {
  __shared__ int s[512];
  int t = threadIdx.x, i = blockIdx.x * 512 + t;
  int v = (i < N_NODES) ? deg[i] : 0;
  s[t] = v;
  __syncthreads();
  for (int off = 1; off < 512; off <<= 1) {   // Hillis-Steele inclusive scan
    int u = (t >= off) ? s[t - off] : 0;
    __syncthreads();
    s[t] += u;
    __syncthreads();
  }
  if (i < N_NODES) {
    int excl = partial[blockIdx.x] + s[t] - v;
    rowptr[i] = excl;
    wofs[i]   = excl;
    if (i == N_NODES - 1) rowptr[N_NODES] = excl + v;
  }
}

__global__ void k_scatter(const int* __restrict__ ei, int* __restrict__ wofs,
                          int* __restrict__ csr_src) {
  int e = blockIdx.x * blockDim.x + threadIdx.x;
  if (e >= EA) return;
  int src, dst;
  if (e < N_EDGES) { src = ei[e]; dst = ei[N_EDGES + e]; }
  else             { src = e - N_EDGES; dst = src; }
  int pos = atomicAdd(&wofs[dst], 1);
  csr_src[pos] = src;
}

// ---------------- casts: x -> bf16 (row-major), W1 -> bf16 transposed [256][512] ----------------
__global__ __launch_bounds__(256) void k_cast_x(const float* __restrict__ x, u32* __restrict__ xb) {
  size_t i = (size_t)blockIdx.x * 256 + threadIdx.x;   // one thread = 8 floats
  if (i >= (size_t)N_NODES * IN_CH / 8) return;
  const float4* src = (const float4*)(x + i * 8);
  float4 v0 = src[0], v1 = src[1];
  uint4 o;
  o.x = pack2(v0.x, v0.y); o.y = pack2(v0.z, v0.w);
  o.z = pack2(v1.x, v1.y); o.w = pack2(v1.z, v1.w);
  ((uint4*)xb)[i] = o;
}

__global__ __launch_bounds__(256) void k_cast_w1t(const float* __restrict__ W1, u16* __restrict__ BT) {
  int id = blockIdx.x * 256 + threadIdx.x;   // id = n*512 + k
  if (id >= D1 * IN_CH) return;
  int n = id >> 9, k = id & 511;
  BT[id] = f2bf(W1[(size_t)k * D1 + n]);
}

// ---------------- GEMM1 (bf16 MFMA): h1b[M,256] (bf16) = xb[M,512] @ W1T^T ----------------
__global__ __launch_bounds__(256) void k_gemm1_mfma(const u16* __restrict__ A,   // [M,512] bf16
                                                    const u16* __restrict__ BT,  // [256,512] bf16
                                                    u16* __restrict__ Cb) {      // [M,256] bf16
  __shared__ u16 As[128 * 32];   // 8 KB
  __shared__ u16 Bs[128 * 32];   // 8 KB
  const int M = N_NODES;
  int bm = blockIdx.x * 128;
  int bn = blockIdx.y * 128;
  int t = threadIdx.x;
  int lane = t & 63, wave = t >> 6;
  int wm = (wave & 1) * 64, wn = (wave >> 1) * 64;

  int ldrow = wave * 16 + (lane >> 2);
  int ldk   = (lane & 3) * 8;
  int arow0 = bm + ldrow;       if (arow0 >= M) arow0 = M - 1;
  int arow1 = bm + 64 + ldrow;  if (arow1 >= M) arow1 = M - 1;
  int brow0 = bn + ldrow;
  int brow1 = bn + 64 + ldrow;
  u16* asd0 = &As[(wave * 16) * 32];
  u16* asd1 = &As[(64 + wave * 16) * 32];
  u16* bsd0 = &Bs[(wave * 16) * 32];
  u16* bsd1 = &Bs[(64 + wave * 16) * 32];

  int am = wm + (lane & 15);
  int bnn = wn + (lane & 15);
  int kq = (lane >> 4) * 8;

  f32x4 acc[4][4] = {};

  for (int k0 = 0; k0 < IN_CH; k0 += 32) {
    __builtin_amdgcn_global_load_lds(
        (const __attribute__((address_space(1))) void*)&A[(size_t)arow0 * IN_CH + k0 + ldk],
        (__attribute__((address_space(3))) void*)asd0, 16, 0, 0);
    __builtin_amdgcn_global_load_lds(
        (const __attribute__((address_space(1))) void*)&A[(size_t)arow1 * IN_CH + k0 + ldk],
        (__attribute__((address_space(3))) void*)asd1, 16, 0, 0);
    __builtin_amdgcn_global_load_lds(
        (const __attribute__((address_space(1))) void*)&BT[(size_t)brow0 * IN_CH + k0 + ldk],
        (__attribute__((address_space(3))) void*)bsd0, 16, 0, 0);
    __builtin_amdgcn_global_load_lds(
        (const __attribute__((address_space(1))) void*)&BT[(size_t)brow1 * IN_CH + k0 + ldk],
        (__attribute__((address_space(3))) void*)bsd1, 16, 0, 0);
    __syncthreads();

    bf16x8 af[4], bfr[4];
    #pragma unroll
    for (int i = 0; i < 4; ++i)
      af[i] = *(const bf16x8*)&As[(am + i * 16) * 32 + kq];
    #pragma unroll
    for (int j = 0; j < 4; ++j)
      bfr[j] = *(const bf16x8*)&Bs[(bnn + j * 16) * 32 + kq];
    #pragma unroll
    for (int i = 0; i < 4; ++i)
      #pragma unroll
      for (int j = 0; j < 4; ++j)
        acc[i][j] = __builtin_amdgcn_mfma_f32_16x16x32_bf16(af[i], bfr[j], acc[i][j], 0, 0, 0);
    __syncthreads();
  }

  #pragma unroll
  for (int i = 0; i < 4; ++i) {
    #pragma unroll
    for (int j = 0; j < 4; ++j) {
      int col = bn + wn + j * 16 + (lane & 15);
      int rowb = bm + wm + i * 16 + (lane >> 4) * 4;
      #pragma unroll
      for (int r = 0; r < 4; ++r) {
        int row = rowb + r;
        if (row < M) Cb[(size_t)row * D1 + col] = f2bf(acc[i][j][r]);
      }
    }
  }
}

// ---------------- attention logits per node, layer 1 (wave per node, bf16 h1) ----------------
__global__ __launch_bounds__(256) void k_al1(const u16* __restrict__ h1b,
                                             const float* __restrict__ att_s,
                                             const float* __restrict__ att_d,
                                             float* __restrict__ al_s,
                                             float* __restrict__ al_d) {
  int node = (blockIdx.x * 256 + threadIdx.x) >> 6;
  int lane = threadIdx.x & 63;
  if (node >= N_NODES) return;
  uint2 hv = *(const uint2*)&h1b[(size_t)node * 256 + lane * 4];
  float v0 = bflo(hv.x), v1 = bfhi(hv.x), v2 = bflo(hv.y), v3 = bfhi(hv.y);
  float4 as = *(const float4*)&att_s[lane * 4];
  float4 ad = *(const float4*)&att_d[lane * 4];
  float ps = v0*as.x + v1*as.y + v2*as.z + v3*as.w;
  float pd = v0*ad.x + v1*ad.y + v2*ad.z + v3*ad.w;
  for (int s = 1; s < 8; s <<= 1) {
    ps += __shfl_xor(ps, s, 64);
    pd += __shfl_xor(pd, s, 64);
  }
  if ((lane & 7) == 0) {
    al_s[node * 8 + (lane >> 3)] = ps;
    al_d[node * 8 + (lane >> 3)] = pd;
  }
}

// ---------------- layer-1 softmax-aggregate + bias + ELU, fused single-pass ----------------
// out = (sum_e p_e * h_src) / (sum_e p_e); each lane sees all edges so dsum needs no reduce.
// 4x unrolled for memory-level parallelism. Writes x2 in bf16.
__global__ __launch_bounds__(256) void k_agg1(const int* __restrict__ rowptr,
                                              const int* __restrict__ csr_src,
                                              const float* __restrict__ al_s,
                                              const float* __restrict__ al_d,
                                              const u16* __restrict__ h1b,
                                              const float* __restrict__ b1,
                                              u32* __restrict__ x2b) {
  int node = (blockIdx.x * 256 + threadIdx.x) >> 6;
  int lane = threadIdx.x & 63;
  if (node >= N_NODES) return;
  int start = rowptr[node], end = rowptr[node + 1];
  int h3 = lane >> 3;
  float aldv3 = al_d[node * 8 + h3];
  size_t choff = (size_t)lane * 4;
  float dsum = 0.f;
  float4 acc = make_float4(0.f, 0.f, 0.f, 0.f);
  int idx = start;
  for (; idx + 4 <= end; idx += 4) {
    int s0 = csr_src[idx + 0];
    int s1 = csr_src[idx + 1];
    int s2 = csr_src[idx + 2];
    int s3 = csr_src[idx + 3];
    uint2 hv0 = *(const uint2*)&h1b[(size_t)s0 * D1 + choff];
    uint2 hv1 = *(const uint2*)&h1b[(size_t)s1 * D1 + choff];
    uint2 hv2 = *(const uint2*)&h1b[(size_t)s2 * D1 + choff];
    uint2 hv3 = *(const uint2*)&h1b[(size_t)s3 * D1 + choff];
    float e0 = al_s[s0 * 8 + h3] + aldv3;
    float e1 = al_s[s1 * 8 + h3] + aldv3;
    float e2 = al_s[s2 * 8 + h3] + aldv3;
    float e3 = al_s[s3 * 8 + h3] + aldv3;
    e0 = (e0 > 0.f) ? e0 : NEG * e0;
    e1 = (e1 > 0.f) ? e1 : NEG * e1;
    e2 = (e2 > 0.f) ? e2 : NEG * e2;
    e3 = (e3 > 0.f) ? e3 : NEG * e3;
    float p0 = __expf(e0), p1 = __expf(e1), p2 = __expf(e2), p3 = __expf(e3);
    dsum += (p0 + p1) + (p2 + p3);
    acc.x += p0 * bflo(hv0.x) + p1 * bflo(hv1.x) + p2 * bflo(hv2.x) + p3 * bflo(hv3.x);
    acc.y += p0 * bfhi(hv0.x) + p1 * bfhi(hv1.x) + p2 * bfhi(hv2.x) + p3 * bfhi(hv3.x);
    acc.z += p0 * bflo(hv0.y) + p1 * bflo(hv1.y) + p2 * bflo(hv2.y) + p3 * bflo(hv3.y);
    acc.w += p0 * bfhi(hv0.y) + p1 * bfhi(hv1.y) + p2 * bfhi(hv2.y) + p3 * bfhi(hv3.y);
  }
  for (; idx < end; ++idx) {
    int s0 = csr_src[idx];
    uint2 hv0 = *(const uint2*)&h1b[(size_t)s0 * D1 + choff];
    float e0 = al_s[s0 * 8 + h3] + aldv3;
    e0 = (e0 > 0.f) ? e0 : NEG * e0;
    float p0 = __expf(e0);
    dsum += p0;
    acc.x += p0 * bflo(hv0.x);
    acc.y += p0 * bfhi(hv0.x);
    acc.z += p0 * bflo(hv0.y);
    acc.w += p0 * bfhi(hv0.y);
  }
  float inv = 1.f / (dsum + 1e-16f);
  float4 bb = *(const float4*)&b1[lane * 4];
  float vx = acc.x * inv + bb.x; vx = vx > 0.f ? vx : __expf(vx) - 1.f;
  float vy = acc.y * inv + bb.y; vy = vy > 0.f ? vy : __expf(vy) - 1.f;
  float vz = acc.z * inv + bb.z; vz = vz > 0.f ? vz : __expf(vz) - 1.f;
  float vw = acc.w * inv + bb.w; vw = vw > 0.f ? vw : __expf(vw) - 1.f;
  ((uint2*)x2b)[(size_t)node * 64 + lane] = make_uint2(pack2(vx, vy), pack2(vz, vw));
}

// ---------------- GEMM2: h2[M,40] = x2b[M,256](bf16) @ W2[256,40] ----------------
__global__ __launch_bounds__(320) void k_gemm2(const u32* __restrict__ x2b,
                                               const float* __restrict__ W2,
                                               float* __restrict__ h2) {
  __shared__ float Ws[D1 * NCLS];   // 40 KB
  int t = threadIdx.x;
  for (int i = t; i < D1 * NCLS; i += 320) Ws[i] = W2[i];
  __syncthreads();
  int r = blockIdx.x * 8 + t / NCLS;
  int c = t % NCLS;
  if (r >= N_NODES) return;
  float acc = 0.f;
  const u32* xr = &x2b[(size_t)r * (D1 / 2)];
  for (int k = 0; k < D1; k += 8) {
    uint4 xv = *(const uint4*)&xr[k / 2];
    acc += bflo(xv.x) * Ws[(k+0)*NCLS + c] + bfhi(xv.x) * Ws[(k+1)*NCLS + c]
         + bflo(xv.y) * Ws[(k+2)*NCLS + c] + bfhi(xv.y) * Ws[(k+3)*NCLS + c]
         + bflo(xv.z) * Ws[(k+4)*NCLS + c] + bfhi(xv.z) * Ws[(k+5)*NCLS + c]
         + bflo(xv.w) * Ws[(k+6)*NCLS + c] + bfhi(xv.w) * Ws[(k+7)*NCLS + c];
  }
  h2[(size_t)r * NCLS + c] = acc;
}

__global__ void k_al2(const float* __restrict__ h2, const float* __restrict__ att_s,
                      const float* __restrict__ att_d,
                      float* __restrict__ al_s, float* __restrict__ al_d) {
  int n = blockIdx.x * blockDim.x + threadIdx.x;
  if (n >= N_NODES) return;
  float ps = 0.f, pd = 0.f;
  const float* hr = &h2[(size_t)n * NCLS];
  for (int c = 0; c < NCLS; ++c) { float v = hr[c]; ps += v * att_s[c]; pd += v * att_d[c]; }
  al_s[n] = ps; al_d[n] = pd;
}

// ---------------- layer-2 softmax-aggregate + bias, fused single-pass, 4x unrolled ----------------
__global__ __launch_bounds__(256) void k_agg2(const int* __restrict__ rowptr,
                                              const int* __restrict__ csr_src,
                                              const float* __restrict__ al_s,
                                              const float* __restrict__ al_d,
                                              const float* __restrict__ h2,
                                              const float* __restrict__ b2,
                                              float* __restrict__ out) {
  int node = (blockIdx.x * 256 + threadIdx.x) >> 6;
  int lane = threadIdx.x & 63;
  if (node >= N_NODES) return;
  int start = rowptr[node], end = rowptr[node + 1];
  float aldv = al_d[node];
  int cl = (lane < NCLS) ? lane : 0;         // lanes >= 40 duplicate lane 0 (discarded)
  float dsum = 0.f, acc = 0.f;
  int idx = start;
  for (; idx + 4 <= end; idx += 4) {
    int s0 = csr_src[idx + 0];
    int s1 = csr_src[idx + 1];
    int s2 = csr_src[idx + 2];
    int s3 = csr_src[idx + 3];
    float g0 = h2[(size_t)s0 * NCLS + cl];
    float g1 = h2[(size_t)s1 * NCLS + cl];
    float g2 = h2[(size_t)s2 * NCLS + cl];
    float g3 = h2[(size_t)s3 * NCLS + cl];
    float e0 = al_s[s0] + aldv;
    float e1 = al_s[s1] + aldv;
    float e2 = al_s[s2] + aldv;
    float e3 = al_s[s3] + aldv;
    e0 = (e0 > 0.f) ? e0 : NEG * e0;
    e1 = (e1 > 0.f) ? e1 : NEG * e1;
    e2 = (e2 > 0.f) ? e2 : NEG * e2;
    e3 = (e3 > 0.f) ? e3 : NEG * e3;
    float p0 = __expf(e0), p1 = __expf(e1), p2 = __expf(e2), p3 = __expf(e3);
    dsum += (p0 + p1) + (p2 + p3);
    acc += p0 * g0 + p1 * g1 + p2 * g2 + p3 * g3;
  }
  for (; idx < end; ++idx) {
    int s0 = csr_src[idx];
    float g0 = h2[(size_t)s0 * NCLS + cl];
    float e0 = al_s[s0] + aldv;
    e0 = (e0 > 0.f) ? e0 : NEG * e0;
    float p0 = __expf(e0);
    dsum += p0;
    acc += p0 * g0;
  }
  float inv = 1.f / (dsum + 1e-16f);
  if (lane < NCLS) out[(size_t)node * NCLS + lane] = acc * inv + b2[lane];
}

extern "C" void kernel_launch(void* const* d_in, const int* in_sizes, int n_in,
                              void* d_out, int out_size, void* d_ws, size_t ws_size,
                              hipStream_t stream) {
  const float* x   = (const float*)d_in[0];
  const int*   ei  = (const int*)d_in[1];
  const float* W1  = (const float*)d_in[2];
  const float* as1 = (const float*)d_in[3];
  const float* ad1 = (const float*)d_in[4];
  const float* b1  = (const float*)d_in[5];
  const float* W2  = (const float*)d_in[6];
  const float* as2 = (const float*)d_in[7];
  const float* ad2 = (const float*)d_in[8];
  const float* b2  = (const float*)d_in[9];
  float* out = (float*)d_out;

  // workspace carve-up (~118 MB)
  char* p = (char*)d_ws;
  auto alloc = [&](size_t bytes) { char* r = p; p += (bytes + 15) & ~size_t(15); return r; };
  u16*  h1b    = (u16*)alloc((size_t)N_NODES * D1 * 2);     // 25.6 MB bf16
  u16*  xb     = (u16*)alloc((size_t)N_NODES * IN_CH * 2);  // 51.2 MB bf16
  u32*  x2b    = (u32*)alloc((size_t)N_NODES * D1 * 2);     // 25.6 MB bf16 (packed pairs)
  float* h2    = (float*)alloc((size_t)N_NODES * NCLS * 4); // 8 MB
  float* al_s1 = (float*)alloc((size_t)N_NODES * 8 * 4);
  float* al_d1 = (float*)alloc((size_t)N_NODES * 8 * 4);
  float* al_s2 = (float*)alloc((size_t)N_NODES * 4);
  float* al_d2 = (float*)alloc((size_t)N_NODES * 4);
  int* deg     = (int*)alloc((size_t)N_NODES * 4);
  int* rowptr  = (int*)alloc((size_t)(N_NODES + 1) * 4);
  int* wofs    = (int*)alloc((size_t)N_NODES * 4);
  int* partial = (int*)alloc(128 * 4);
  int* csr_src = (int*)alloc((size_t)EA * 4);
  u16* w1t     = (u16*)alloc((size_t)D1 * IN_CH * 2);

  const int NB = (N_NODES + 511) / 512;  // 98

  hipMemsetAsync(deg, 0, (size_t)N_NODES * 4, stream);
  k_hist<<<(EA + 255) / 256, 256, 0, stream>>>(ei, deg);
  k_scan_partial<<<NB, 512, 0, stream>>>(deg, partial);
  k_scan_top<<<1, 64, 0, stream>>>(partial, NB);
  k_scan_final<<<NB, 512, 0, stream>>>(deg, partial, rowptr, wofs);
  k_scatter<<<(EA + 255) / 256, 256, 0, stream>>>(ei, wofs, csr_src);

  k_cast_x<<<(N_NODES * IN_CH / 8 + 255) / 256, 256, 0, stream>>>(x, (u32*)xb);
  k_cast_w1t<<<(D1 * IN_CH + 255) / 256, 256, 0, stream>>>(W1, w1t);

  dim3 g1((N_NODES + 127) / 128, 2);
  k_gemm1_mfma<<<g1, 256, 0, stream>>>(xb, w1t, h1b);

  k_al1<<<(N_NODES + 3) / 4, 256, 0, stream>>>(h1b, as1, ad1, al_s1, al_d1);
  k_agg1<<<(N_NODES + 3) / 4, 256, 0, stream>>>(rowptr, csr_src, al_s1, al_d1, h1b, b1, x2b);

  k_gemm2<<<(N_NODES + 7) / 8, 320, 0, stream>>>(x2b, W2, h2);
  k_al2<<<(N_NODES + 255) / 256, 256, 0, stream>>>(h2, as2, ad2, al_s2, al_d2);
  k_agg2<<<(N_NODES + 3) / 4, 256, 0, stream>>>(rowptr, csr_src, al_s2, al_d2, h2, b2, out);
}

// Round 5
// 446.204 us; speedup vs baseline: 1.6756x; 1.1237x over previous
//
#include <hip/hip_runtime.h>

#define N_NODES 50000
#define N_EDGES 800000
#define EA (N_EDGES + N_NODES)   // 850000 edges incl. self-loops
#define IN_CH 512
#define D1 256
#define HID 32
#define HEADS 8
#define NCLS 40
#define NCLS_P 48                // padded to 3 x 16 col-tiles
#define W2LD 264                 // LDS row stride (u16) for W2 tile: 264*2B=528B, conflict-free
#define NEG 0.2f

typedef unsigned short u16;
typedef unsigned int u32;
typedef __attribute__((ext_vector_type(8))) short bf16x8;
typedef __attribute__((ext_vector_type(4))) float f32x4;

__device__ inline u16 f2bf(float f) {           // round-to-nearest-even fp32->bf16
  u32 u = __float_as_uint(f);
  u += 0x7FFFu + ((u >> 16) & 1u);
  return (u16)(u >> 16);
}
__device__ inline u32 pack2(float a, float b) {
  return (u32)f2bf(a) | ((u32)f2bf(b) << 16);
}
__device__ inline float bflo(u32 v) { return __uint_as_float(v << 16); }
__device__ inline float bfhi(u32 v) { return __uint_as_float(v & 0xffff0000u); }

// ---------------- CSR build (by dst) ----------------
__global__ void k_hist(const int* __restrict__ ei, int* __restrict__ deg) {
  int e = blockIdx.x * blockDim.x + threadIdx.x;
  if (e >= EA) return;
  int dst = (e < N_EDGES) ? ei[N_EDGES + e] : (e - N_EDGES);
  atomicAdd(&deg[dst], 1);
}

__global__ void k_scan_partial(const int* __restrict__ deg, int* __restrict__ partial) {
  __shared__ int s[512];
  int i = blockIdx.x * 512 + threadIdx.x;
  s[threadIdx.x] = (i < N_NODES) ? deg[i] : 0;
  __syncthreads();
  for (int off = 256; off > 0; off >>= 1) {
    if (threadIdx.x < off) s[threadIdx.x] += s[threadIdx.x + off];
    __syncthreads();
  }
  if (threadIdx.x == 0) partial[blockIdx.x] = s[0];
}

__global__ void k_scan_top(int* partial, int nb) {
  if (threadIdx.x || blockIdx.x) return;
  int acc = 0;
  for (int i = 0; i < nb; ++i) { int v = partial[i]; partial[i] = acc; acc += v; }
}

__global__ void k_scan_final(const int* __restrict__ deg, const int* __restrict__ partial,
                             int* __restrict__ rowptr, int* __restrict__ wofs) {
  __shared__ int s[512];
  int t = threadIdx.x, i = blockIdx.x * 512 + t;
  int v = (i < N_NODES) ? deg[i] : 0;
  s[t] = v;
  __syncthreads();
  for (int off = 1; off < 512; off <<= 1) {   // Hillis-Steele inclusive scan
    int u = (t >= off) ? s[t - off] : 0;
    __syncthreads();
    s[t] += u;
    __syncthreads();
  }
  if (i < N_NODES) {
    int excl = partial[blockIdx.x] + s[t] - v;
    rowptr[i] = excl;
    wofs[i]   = excl;
    if (i == N_NODES - 1) rowptr[N_NODES] = excl + v;
  }
}

__global__ void k_scatter(const int* __restrict__ ei, int* __restrict__ wofs,
                          int* __restrict__ csr_src) {
  int e = blockIdx.x * blockDim.x + threadIdx.x;
  if (e >= EA) return;
  int src, dst;
  if (e < N_EDGES) { src = ei[e]; dst = ei[N_EDGES + e]; }
  else             { src = e - N_EDGES; dst = src; }
  int pos = atomicAdd(&wofs[dst], 1);
  csr_src[pos] = src;
}

// ---------------- casts ----------------
__global__ __launch_bounds__(256) void k_cast_x(const float* __restrict__ x, u32* __restrict__ xb) {
  size_t i = (size_t)blockIdx.x * 256 + threadIdx.x;   // one thread = 8 floats
  if (i >= (size_t)N_NODES * IN_CH / 8) return;
  const float4* src = (const float4*)(x + i * 8);
  float4 v0 = src[0], v1 = src[1];
  uint4 o;
  o.x = pack2(v0.x, v0.y); o.y = pack2(v0.z, v0.w);
  o.z = pack2(v1.x, v1.y); o.w = pack2(v1.z, v1.w);
  ((uint4*)xb)[i] = o;
}

__global__ __launch_bounds__(256) void k_cast_w1t(const float* __restrict__ W1, u16* __restrict__ BT) {
  int id = blockIdx.x * 256 + threadIdx.x;   // id = n*512 + k
  if (id >= D1 * IN_CH) return;
  int n = id >> 9, k = id & 511;
  BT[id] = f2bf(W1[(size_t)k * D1 + n]);
}

// W2 [256,40] fp32 -> w2t bf16 [48][256] (rows 40..47 zero)
__global__ __launch_bounds__(256) void k_cast_w2t(const float* __restrict__ W2, u16* __restrict__ BT) {
  int id = blockIdx.x * 256 + threadIdx.x;   // id = n*256 + k
  if (id >= NCLS_P * D1) return;
  int n = id >> 8, k = id & 255;
  BT[id] = (n < NCLS) ? f2bf(W2[(size_t)k * NCLS + n]) : (u16)0;
}

// ---------------- GEMM1 (bf16 MFMA): h1b[M,256] (bf16) = xb[M,512] @ W1T^T ----------------
__global__ __launch_bounds__(256) void k_gemm1_mfma(const u16* __restrict__ A,   // [M,512] bf16
                                                    const u16* __restrict__ BT,  // [256,512] bf16
                                                    u16* __restrict__ Cb) {      // [M,256] bf16
  __shared__ u16 As[128 * 32];   // 8 KB
  __shared__ u16 Bs[128 * 32];   // 8 KB
  const int M = N_NODES;
  int bm = blockIdx.x * 128;
  int bn = blockIdx.y * 128;
  int t = threadIdx.x;
  int lane = t & 63, wave = t >> 6;
  int wm = (wave & 1) * 64, wn = (wave >> 1) * 64;

  int ldrow = wave * 16 + (lane >> 2);
  int ldk   = (lane & 3) * 8;
  int arow0 = bm + ldrow;       if (arow0 >= M) arow0 = M - 1;
  int arow1 = bm + 64 + ldrow;  if (arow1 >= M) arow1 = M - 1;
  int brow0 = bn + ldrow;
  int brow1 = bn + 64 + ldrow;
  u16* asd0 = &As[(wave * 16) * 32];
  u16* asd1 = &As[(64 + wave * 16) * 32];
  u16* bsd0 = &Bs[(wave * 16) * 32];
  u16* bsd1 = &Bs[(64 + wave * 16) * 32];

  int am = wm + (lane & 15);
  int bnn = wn + (lane & 15);
  int kq = (lane >> 4) * 8;

  f32x4 acc[4][4] = {};

  for (int k0 = 0; k0 < IN_CH; k0 += 32) {
    __builtin_amdgcn_global_load_lds(
        (const __attribute__((address_space(1))) void*)&A[(size_t)arow0 * IN_CH + k0 + ldk],
        (__attribute__((address_space(3))) void*)asd0, 16, 0, 0);
    __builtin_amdgcn_global_load_lds(
        (const __attribute__((address_space(1))) void*)&A[(size_t)arow1 * IN_CH + k0 + ldk],
        (__attribute__((address_space(3))) void*)asd1, 16, 0, 0);
    __builtin_amdgcn_global_load_lds(
        (const __attribute__((address_space(1))) void*)&BT[(size_t)brow0 * IN_CH + k0 + ldk],
        (__attribute__((address_space(3))) void*)bsd0, 16, 0, 0);
    __builtin_amdgcn_global_load_lds(
        (const __attribute__((address_space(1))) void*)&BT[(size_t)brow1 * IN_CH + k0 + ldk],
        (__attribute__((address_space(3))) void*)bsd1, 16, 0, 0);
    __syncthreads();

    bf16x8 af[4], bfr[4];
    #pragma unroll
    for (int i = 0; i < 4; ++i)
      af[i] = *(const bf16x8*)&As[(am + i * 16) * 32 + kq];
    #pragma unroll
    for (int j = 0; j < 4; ++j)
      bfr[j] = *(const bf16x8*)&Bs[(bnn + j * 16) * 32 + kq];
    #pragma unroll
    for (int i = 0; i < 4; ++i)
      #pragma unroll
      for (int j = 0; j < 4; ++j)
        acc[i][j] = __builtin_amdgcn_mfma_f32_16x16x32_bf16(af[i], bfr[j], acc[i][j], 0, 0, 0);
    __syncthreads();
  }

  #pragma unroll
  for (int i = 0; i < 4; ++i) {
    #pragma unroll
    for (int j = 0; j < 4; ++j) {
      int col = bn + wn + j * 16 + (lane & 15);
      int rowb = bm + wm + i * 16 + (lane >> 4) * 4;
      #pragma unroll
      for (int r = 0; r < 4; ++r) {
        int row = rowb + r;
        if (row < M) Cb[(size_t)row * D1 + col] = f2bf(acc[i][j][r]);
      }
    }
  }
}

// ---------------- attention logits per node, layer 1 (wave per node, bf16 h1) ----------------
__global__ __launch_bounds__(256) void k_al1(const u16* __restrict__ h1b,
                                             const float* __restrict__ att_s,
                                             const float* __restrict__ att_d,
                                             float* __restrict__ al_s,
                                             float* __restrict__ al_d) {
  int node = (blockIdx.x * 256 + threadIdx.x) >> 6;
  int lane = threadIdx.x & 63;
  if (node >= N_NODES) return;
  uint2 hv = *(const uint2*)&h1b[(size_t)node * 256 + lane * 4];
  float v0 = bflo(hv.x), v1 = bfhi(hv.x), v2 = bflo(hv.y), v3 = bfhi(hv.y);
  float4 as = *(const float4*)&att_s[lane * 4];
  float4 ad = *(const float4*)&att_d[lane * 4];
  float ps = v0*as.x + v1*as.y + v2*as.z + v3*as.w;
  float pd = v0*ad.x + v1*ad.y + v2*ad.z + v3*ad.w;
  for (int s = 1; s < 8; s <<= 1) {
    ps += __shfl_xor(ps, s, 64);
    pd += __shfl_xor(pd, s, 64);
  }
  if ((lane & 7) == 0) {
    al_s[node * 8 + (lane >> 3)] = ps;
    al_d[node * 8 + (lane >> 3)] = pd;
  }
}

// ---------------- layer-1 softmax-aggregate + bias + ELU, fused single-pass, 4x unrolled ----------------
__global__ __launch_bounds__(256) void k_agg1(const int* __restrict__ rowptr,
                                              const int* __restrict__ csr_src,
                                              const float* __restrict__ al_s,
                                              const float* __restrict__ al_d,
                                              const u16* __restrict__ h1b,
                                              const float* __restrict__ b1,
                                              u32* __restrict__ x2b) {
  int node = (blockIdx.x * 256 + threadIdx.x) >> 6;
  int lane = threadIdx.x & 63;
  if (node >= N_NODES) return;
  int start = rowptr[node], end = rowptr[node + 1];
  int h3 = lane >> 3;
  float aldv3 = al_d[node * 8 + h3];
  size_t choff = (size_t)lane * 4;
  float dsum = 0.f;
  float4 acc = make_float4(0.f, 0.f, 0.f, 0.f);
  int idx = start;
  for (; idx + 4 <= end; idx += 4) {
    int s0 = csr_src[idx + 0];
    int s1 = csr_src[idx + 1];
    int s2 = csr_src[idx + 2];
    int s3 = csr_src[idx + 3];
    uint2 hv0 = *(const uint2*)&h1b[(size_t)s0 * D1 + choff];
    uint2 hv1 = *(const uint2*)&h1b[(size_t)s1 * D1 + choff];
    uint2 hv2 = *(const uint2*)&h1b[(size_t)s2 * D1 + choff];
    uint2 hv3 = *(const uint2*)&h1b[(size_t)s3 * D1 + choff];
    float e0 = al_s[s0 * 8 + h3] + aldv3;
    float e1 = al_s[s1 * 8 + h3] + aldv3;
    float e2 = al_s[s2 * 8 + h3] + aldv3;
    float e3 = al_s[s3 * 8 + h3] + aldv3;
    e0 = (e0 > 0.f) ? e0 : NEG * e0;
    e1 = (e1 > 0.f) ? e1 : NEG * e1;
    e2 = (e2 > 0.f) ? e2 : NEG * e2;
    e3 = (e3 > 0.f) ? e3 : NEG * e3;
    float p0 = __expf(e0), p1 = __expf(e1), p2 = __expf(e2), p3 = __expf(e3);
    dsum += (p0 + p1) + (p2 + p3);
    acc.x += p0 * bflo(hv0.x) + p1 * bflo(hv1.x) + p2 * bflo(hv2.x) + p3 * bflo(hv3.x);
    acc.y += p0 * bfhi(hv0.x) + p1 * bfhi(hv1.x) + p2 * bfhi(hv2.x) + p3 * bfhi(hv3.x);
    acc.z += p0 * bflo(hv0.y) + p1 * bflo(hv1.y) + p2 * bflo(hv2.y) + p3 * bflo(hv3.y);
    acc.w += p0 * bfhi(hv0.y) + p1 * bfhi(hv1.y) + p2 * bfhi(hv2.y) + p3 * bfhi(hv3.y);
  }
  for (; idx < end; ++idx) {
    int s0 = csr_src[idx];
    uint2 hv0 = *(const uint2*)&h1b[(size_t)s0 * D1 + choff];
    float e0 = al_s[s0 * 8 + h3] + aldv3;
    e0 = (e0 > 0.f) ? e0 : NEG * e0;
    float p0 = __expf(e0);
    dsum += p0;
    acc.x += p0 * bflo(hv0.x);
    acc.y += p0 * bfhi(hv0.x);
    acc.z += p0 * bflo(hv0.y);
    acc.w += p0 * bfhi(hv0.y);
  }
  float inv = 1.f / (dsum + 1e-16f);
  float4 bb = *(const float4*)&b1[lane * 4];
  float vx = acc.x * inv + bb.x; vx = vx > 0.f ? vx : __expf(vx) - 1.f;
  float vy = acc.y * inv + bb.y; vy = vy > 0.f ? vy : __expf(vy) - 1.f;
  float vz = acc.z * inv + bb.z; vz = vz > 0.f ? vz : __expf(vz) - 1.f;
  float vw = acc.w * inv + bb.w; vw = vw > 0.f ? vw : __expf(vw) - 1.f;
  ((uint2*)x2b)[(size_t)node * 64 + lane] = make_uint2(pack2(vx, vy), pack2(vz, vw));
}

// ---------------- GEMM2 (bf16 MFMA): h2b[M,40] (bf16) = x2b[M,256] @ W2T^T ----------------
// 128-row strip per block, 4 waves x 32 rows; cols 0..47 (3 tiles); W2T fully LDS-resident.
__global__ __launch_bounds__(256) void k_gemm2_mfma(const u16* __restrict__ A,    // [M,256] bf16
                                                    const u16* __restrict__ W2T,  // [48][256] bf16
                                                    u16* __restrict__ h2b) {      // [M,40] bf16
  __shared__ u16 As[128 * 32];          // 8 KB
  __shared__ u16 Ws[NCLS_P * W2LD];     // 48*264*2 = 25.3 KB, stride 264 breaks conflicts
  const int M = N_NODES;
  int bm = blockIdx.x * 128;
  int t = threadIdx.x;
  int lane = t & 63, wave = t >> 6;
  int wm = wave * 32;

  // stage W2T once (u32 copies)
  for (int i = t; i < NCLS_P * (D1 / 2); i += 256) {
    int n = i >> 7, k2 = i & 127;
    *(u32*)&Ws[n * W2LD + k2 * 2] = ((const u32*)W2T)[i];
  }

  int ldrow = wave * 16 + (lane >> 2);
  int ldk   = (lane & 3) * 8;
  int arow0 = bm + ldrow;       if (arow0 >= M) arow0 = M - 1;
  int arow1 = bm + 64 + ldrow;  if (arow1 >= M) arow1 = M - 1;
  u16* asd0 = &As[(wave * 16) * 32];
  u16* asd1 = &As[(64 + wave * 16) * 32];

  int am = wm + (lane & 15);
  int nn = lane & 15;
  int kq = (lane >> 4) * 8;

  f32x4 acc[2][3] = {};

  for (int k0 = 0; k0 < D1; k0 += 32) {
    __builtin_amdgcn_global_load_lds(
        (const __attribute__((address_space(1))) void*)&A[(size_t)arow0 * D1 + k0 + ldk],
        (__attribute__((address_space(3))) void*)asd0, 16, 0, 0);
    __builtin_amdgcn_global_load_lds(
        (const __attribute__((address_space(1))) void*)&A[(size_t)arow1 * D1 + k0 + ldk],
        (__attribute__((address_space(3))) void*)asd1, 16, 0, 0);
    __syncthreads();

    bf16x8 af[2], bfr[3];
    #pragma unroll
    for (int i = 0; i < 2; ++i)
      af[i] = *(const bf16x8*)&As[(am + i * 16) * 32 + kq];
    #pragma unroll
    for (int j = 0; j < 3; ++j)
      bfr[j] = *(const bf16x8*)&Ws[(j * 16 + nn) * W2LD + k0 + kq];
    #pragma unroll
    for (int i = 0; i < 2; ++i)
      #pragma unroll
      for (int j = 0; j < 3; ++j)
        acc[i][j] = __builtin_amdgcn_mfma_f32_16x16x32_bf16(af[i], bfr[j], acc[i][j], 0, 0, 0);
    __syncthreads();
  }

  #pragma unroll
  for (int i = 0; i < 2; ++i) {
    #pragma unroll
    for (int j = 0; j < 3; ++j) {
      int col = j * 16 + (lane & 15);
      if (col >= NCLS) continue;
      int rowb = bm + wm + i * 16 + (lane >> 4) * 4;
      #pragma unroll
      for (int r = 0; r < 4; ++r) {
        int row = rowb + r;
        if (row < M) h2b[(size_t)row * NCLS + col] = f2bf(acc[i][j][r]);
      }
    }
  }
}

// ---------------- al2 on bf16 h2 ----------------
__global__ void k_al2(const u32* __restrict__ h2p, const float* __restrict__ att_s,
                      const float* __restrict__ att_d,
                      float* __restrict__ al_s, float* __restrict__ al_d) {
  int n = blockIdx.x * blockDim.x + threadIdx.x;
  if (n >= N_NODES) return;
  float ps = 0.f, pd = 0.f;
  const u32* hr = &h2p[(size_t)n * (NCLS / 2)];
  for (int c = 0; c < NCLS / 2; ++c) {
    u32 v = hr[c];
    ps += bflo(v) * att_s[2 * c] + bfhi(v) * att_s[2 * c + 1];
    pd += bflo(v) * att_d[2 * c] + bfhi(v) * att_d[2 * c + 1];
  }
  al_s[n] = ps; al_d[n] = pd;
}

// ---------------- layer-2 softmax-aggregate + bias, fused, 4x unrolled, bf16 h2 ----------------
// lane l (0..19) owns channels 2l, 2l+1 (u32 gather); all lanes compute dsum.
__global__ __launch_bounds__(256) void k_agg2(const int* __restrict__ rowptr,
                                              const int* __restrict__ csr_src,
                                              const float* __restrict__ al_s,
                                              const float* __restrict__ al_d,
                                              const u32* __restrict__ h2p,
                                              const float* __restrict__ b2,
                                              float* __restrict__ out) {
  int node = (blockIdx.x * 256 + threadIdx.x) >> 6;
  int lane = threadIdx.x & 63;
  if (node >= N_NODES) return;
  int start = rowptr[node], end = rowptr[node + 1];
  float aldv = al_d[node];
  int cl = (lane < NCLS / 2) ? lane : 0;
  float dsum = 0.f, accl = 0.f, acch = 0.f;
  int idx = start;
  for (; idx + 4 <= end; idx += 4) {
    int s0 = csr_src[idx + 0];
    int s1 = csr_src[idx + 1];
    int s2 = csr_src[idx + 2];
    int s3 = csr_src[idx + 3];
    u32 g0 = h2p[(size_t)s0 * (NCLS / 2) + cl];
    u32 g1 = h2p[(size_t)s1 * (NCLS / 2) + cl];
    u32 g2 = h2p[(size_t)s2 * (NCLS / 2) + cl];
    u32 g3 = h2p[(size_t)s3 * (NCLS / 2) + cl];
    float e0 = al_s[s0] + aldv;
    float e1 = al_s[s1] + aldv;
    float e2 = al_s[s2] + aldv;
    float e3 = al_s[s3] + aldv;
    e0 = (e0 > 0.f) ? e0 : NEG * e0;
    e1 = (e1 > 0.f) ? e1 : NEG * e1;
    e2 = (e2 > 0.f) ? e2 : NEG * e2;
    e3 = (e3 > 0.f) ? e3 : NEG * e3;
    float p0 = __expf(e0), p1 = __expf(e1), p2 = __expf(e2), p3 = __expf(e3);
    dsum += (p0 + p1) + (p2 + p3);
    accl += p0 * bflo(g0) + p1 * bflo(g1) + p2 * bflo(g2) + p3 * bflo(g3);
    acch += p0 * bfhi(g0) + p1 * bfhi(g1) + p2 * bfhi(g2) + p3 * bfhi(g3);
  }
  for (; idx < end; ++idx) {
    int s0 = csr_src[idx];
    u32 g0 = h2p[(size_t)s0 * (NCLS / 2) + cl];
    float e0 = al_s[s0] + aldv;
    e0 = (e0 > 0.f) ? e0 : NEG * e0;
    float p0 = __expf(e0);
    dsum += p0;
    accl += p0 * bflo(g0);
    acch += p0 * bfhi(g0);
  }
  float inv = 1.f / (dsum + 1e-16f);
  if (lane < NCLS / 2) {
    out[(size_t)node * NCLS + 2 * lane]     = accl * inv + b2[2 * lane];
    out[(size_t)node * NCLS + 2 * lane + 1] = acch * inv + b2[2 * lane + 1];
  }
}

extern "C" void kernel_launch(void* const* d_in, const int* in_sizes, int n_in,
                              void* d_out, int out_size, void* d_ws, size_t ws_size,
                              hipStream_t stream) {
  const float* x   = (const float*)d_in[0];
  const int*   ei  = (const int*)d_in[1];
  const float* W1  = (const float*)d_in[2];
  const float* as1 = (const float*)d_in[3];
  const float* ad1 = (const float*)d_in[4];
  const float* b1  = (const float*)d_in[5];
  const float* W2  = (const float*)d_in[6];
  const float* as2 = (const float*)d_in[7];
  const float* ad2 = (const float*)d_in[8];
  const float* b2  = (const float*)d_in[9];
  float* out = (float*)d_out;

  // workspace carve-up (~115 MB)
  char* p = (char*)d_ws;
  auto alloc = [&](size_t bytes) { char* r = p; p += (bytes + 15) & ~size_t(15); return r; };
  u16*  h1b    = (u16*)alloc((size_t)N_NODES * D1 * 2);     // 25.6 MB bf16
  u16*  xb     = (u16*)alloc((size_t)N_NODES * IN_CH * 2);  // 51.2 MB bf16
  u32*  x2b    = (u32*)alloc((size_t)N_NODES * D1 * 2);     // 25.6 MB bf16 (packed pairs)
  u16*  h2b    = (u16*)alloc((size_t)N_NODES * NCLS * 2);   // 4 MB bf16
  float* al_s1 = (float*)alloc((size_t)N_NODES * 8 * 4);
  float* al_d1 = (float*)alloc((size_t)N_NODES * 8 * 4);
  float* al_s2 = (float*)alloc((size_t)N_NODES * 4);
  float* al_d2 = (float*)alloc((size_t)N_NODES * 4);
  int* deg     = (int*)alloc((size_t)N_NODES * 4);
  int* rowptr  = (int*)alloc((size_t)(N_NODES + 1) * 4);
  int* wofs    = (int*)alloc((size_t)N_NODES * 4);
  int* partial = (int*)alloc(128 * 4);
  int* csr_src = (int*)alloc((size_t)EA * 4);
  u16* w1t     = (u16*)alloc((size_t)D1 * IN_CH * 2);
  u16* w2t     = (u16*)alloc((size_t)NCLS_P * D1 * 2);

  const int NB = (N_NODES + 511) / 512;  // 98

  hipMemsetAsync(deg, 0, (size_t)N_NODES * 4, stream);
  k_hist<<<(EA + 255) / 256, 256, 0, stream>>>(ei, deg);
  k_scan_partial<<<NB, 512, 0, stream>>>(deg, partial);
  k_scan_top<<<1, 64, 0, stream>>>(partial, NB);
  k_scan_final<<<NB, 512, 0, stream>>>(deg, partial, rowptr, wofs);
  k_scatter<<<(EA + 255) / 256, 256, 0, stream>>>(ei, wofs, csr_src);

  k_cast_x<<<(N_NODES * IN_CH / 8 + 255) / 256, 256, 0, stream>>>(x, (u32*)xb);
  k_cast_w1t<<<(D1 * IN_CH + 255) / 256, 256, 0, stream>>>(W1, w1t);
  k_cast_w2t<<<(NCLS_P * D1 + 255) / 256, 256, 0, stream>>>(W2, w2t);

  dim3 g1((N_NODES + 127) / 128, 2);
  k_gemm1_mfma<<<g1, 256, 0, stream>>>(xb, w1t, h1b);

  k_al1<<<(N_NODES + 3) / 4, 256, 0, stream>>>(h1b, as1, ad1, al_s1, al_d1);
  k_agg1<<<(N_NODES + 3) / 4, 256, 0, stream>>>(rowptr, csr_src, al_s1, al_d1, h1b, b1, x2b);

  k_gemm2_mfma<<<(N_NODES + 127) / 128, 256, 0, stream>>>((const u16*)x2b, w2t, h2b);
  k_al2<<<(N_NODES + 255) / 256, 256, 0, stream>>>((const u32*)h2b, as2, ad2, al_s2, al_d2);
  k_agg2<<<(N_NODES + 3) / 4, 256, 0, stream>>>(rowptr, csr_src, al_s2, al_d2, (const u32*)h2b, b2, out);
}

// Round 6
// 424.603 us; speedup vs baseline: 1.7609x; 1.0509x over previous
//
#include <hip/hip_runtime.h>

#define N_NODES 50000
#define N_EDGES 800000
#define EA (N_EDGES + N_NODES)   // 850000 edges incl. self-loops
#define IN_CH 512
#define D1 256
#define HID 32
#define HEADS 8
#define NCLS 40
#define NCLS_P 48                // padded to 3 x 16 col-tiles
#define W2LD 264                 // LDS row stride (u16) for W2 tile
#define NEG 0.2f

typedef unsigned short u16;
typedef unsigned int u32;
typedef __attribute__((ext_vector_type(8))) short bf16x8;
typedef __attribute__((ext_vector_type(4))) float f32x4;

__device__ inline u16 f2bf(float f) {           // round-to-nearest-even fp32->bf16
  u32 u = __float_as_uint(f);
  u += 0x7FFFu + ((u >> 16) & 1u);
  return (u16)(u >> 16);
}
__device__ inline u32 pack2(float a, float b) {
  return (u32)f2bf(a) | ((u32)f2bf(b) << 16);
}
__device__ inline float bflo(u32 v) { return __uint_as_float(v << 16); }
__device__ inline float bfhi(u32 v) { return __uint_as_float(v & 0xffff0000u); }

// ---------------- CSR build (by dst) ----------------
__global__ void k_hist(const int* __restrict__ ei, int* __restrict__ deg) {
  int e = blockIdx.x * blockDim.x + threadIdx.x;
  if (e >= EA) return;
  int dst = (e < N_EDGES) ? ei[N_EDGES + e] : (e - N_EDGES);
  atomicAdd(&deg[dst], 1);
}

__global__ void k_scan_partial(const int* __restrict__ deg, int* __restrict__ partial) {
  __shared__ int s[512];
  int i = blockIdx.x * 512 + threadIdx.x;
  s[threadIdx.x] = (i < N_NODES) ? deg[i] : 0;
  __syncthreads();
  for (int off = 256; off > 0; off >>= 1) {
    if (threadIdx.x < off) s[threadIdx.x] += s[threadIdx.x + off];
    __syncthreads();
  }
  if (threadIdx.x == 0) partial[blockIdx.x] = s[0];
}

// wave-parallel exclusive scan over nb<=128 partials (one wave, 2 elems/lane)
__global__ void k_scan_top(int* partial, int nb) {
  int lane = threadIdx.x & 63;
  int i0 = lane * 2, i1 = lane * 2 + 1;
  int v0 = (i0 < nb) ? partial[i0] : 0;
  int v1 = (i1 < nb) ? partial[i1] : 0;
  int s = v0 + v1;
  for (int off = 1; off < 64; off <<= 1) {
    int tt = __shfl_up(s, off, 64);
    if (lane >= off) s += tt;
  }
  int excl = s - (v0 + v1);
  if (i0 < nb) partial[i0] = excl;
  if (i1 < nb) partial[i1] = excl + v0;
}

__global__ void k_scan_final(const int* __restrict__ deg, const int* __restrict__ partial,
                             int* __restrict__ rowptr, int* __restrict__ wofs) {
  __shared__ int s[512];
  int t = threadIdx.x, i = blockIdx.x * 512 + t;
  int v = (i < N_NODES) ? deg[i] : 0;
  s[t] = v;
  __syncthreads();
  for (int off = 1; off < 512; off <<= 1) {   // Hillis-Steele inclusive scan
    int u = (t >= off) ? s[t - off] : 0;
    __syncthreads();
    s[t] += u;
    __syncthreads();
  }
  if (i < N_NODES) {
    int excl = partial[blockIdx.x] + s[t] - v;
    rowptr[i] = excl;
    wofs[i]   = excl;
    if (i == N_NODES - 1) rowptr[N_NODES] = excl + v;
  }
}

__global__ void k_scatter(const int* __restrict__ ei, int* __restrict__ wofs,
                          int* __restrict__ csr_src, int* __restrict__ csr_dst) {
  int e = blockIdx.x * blockDim.x + threadIdx.x;
  if (e >= EA) return;
  int src, dst;
  if (e < N_EDGES) { src = ei[e]; dst = ei[N_EDGES + e]; }
  else             { src = e - N_EDGES; dst = src; }
  int pos = atomicAdd(&wofs[dst], 1);
  csr_src[pos] = src;
  csr_dst[pos] = dst;
}

// ---------------- merged weight casts: W1 -> w1t [256][512], W2 -> w2t [48][256] ----------------
__global__ __launch_bounds__(256) void k_cast_w(const float* __restrict__ W1,
                                                const float* __restrict__ W2,
                                                u16* __restrict__ w1t, u16* __restrict__ w2t) {
  int id = blockIdx.x * 256 + threadIdx.x;
  if (id < D1 * IN_CH) {
    int n = id >> 9, k = id & 511;
    w1t[id] = f2bf(W1[(size_t)k * D1 + n]);
  } else {
    int id2 = id - D1 * IN_CH;
    if (id2 < NCLS_P * D1) {
      int n = id2 >> 8, k = id2 & 255;
      w2t[id2] = (n < NCLS) ? f2bf(W2[(size_t)k * NCLS + n]) : (u16)0;
    }
  }
}

// ---------------- GEMM1 (bf16 MFMA, fused fp32->bf16 A-cast): h1b = x @ W1 ----------------
// BM=64, BN=256 (full width, x read once), BK=32; 4 waves, each 32x128 (2x8 16x16x32 tiles).
__global__ __launch_bounds__(256) void k_gemm1_fused(const float* __restrict__ X,  // [M,512] fp32
                                                     const u16* __restrict__ BT,   // [256,512] bf16
                                                     u16* __restrict__ Cb) {       // [M,256] bf16
  __shared__ u16 As[64 * 32];    // 4 KB
  __shared__ u16 Bs[256 * 32];   // 16 KB
  const int M = N_NODES;
  int bm = blockIdx.x * 64;
  int t = threadIdx.x;
  int lane = t & 63, wave = t >> 6;
  int wm = (wave & 1) * 32, wn = (wave >> 1) * 128;

  // A staging: thread t covers row t>>2, k-chunk (t&3)*8 (8 floats -> 8 bf16 = 16B)
  int arow = t >> 2;
  int akofs = (t & 3) * 8;
  int garow = bm + arow; if (garow >= M) garow = M - 1;

  // B staging: wave covers rows wave*64..+63 in 4 lds-DMA issues of 16 rows
  int brow_base = wave * 64;
  int blrow = lane >> 2;
  int bkofs = (lane & 3) * 8;

  int kq = (lane >> 4) * 8;

  f32x4 acc[2][8] = {};

  for (int k0 = 0; k0 < IN_CH; k0 += 32) {
    #pragma unroll
    for (int q = 0; q < 4; ++q) {
      int r0 = brow_base + q * 16;
      __builtin_amdgcn_global_load_lds(
          (const __attribute__((address_space(1))) void*)&BT[(size_t)(r0 + blrow) * IN_CH + k0 + bkofs],
          (__attribute__((address_space(3))) void*)&Bs[r0 * 32], 16, 0, 0);
    }
    const float* xp = &X[(size_t)garow * IN_CH + k0 + akofs];
    float4 v0 = *(const float4*)xp;
    float4 v1 = *(const float4*)(xp + 4);
    uint4 o;
    o.x = pack2(v0.x, v0.y); o.y = pack2(v0.z, v0.w);
    o.z = pack2(v1.x, v1.y); o.w = pack2(v1.z, v1.w);
    *(uint4*)&As[arow * 32 + akofs] = o;
    __syncthreads();

    bf16x8 af[2], bfr[8];
    #pragma unroll
    for (int i = 0; i < 2; ++i)
      af[i] = *(const bf16x8*)&As[(wm + i * 16 + (lane & 15)) * 32 + kq];
    #pragma unroll
    for (int j = 0; j < 8; ++j)
      bfr[j] = *(const bf16x8*)&Bs[(wn + j * 16 + (lane & 15)) * 32 + kq];
    #pragma unroll
    for (int i = 0; i < 2; ++i)
      #pragma unroll
      for (int j = 0; j < 8; ++j)
        acc[i][j] = __builtin_amdgcn_mfma_f32_16x16x32_bf16(af[i], bfr[j], acc[i][j], 0, 0, 0);
    __syncthreads();
  }

  // epilogue: C/D layout col=lane&15, row=(lane>>4)*4+r
  #pragma unroll
  for (int i = 0; i < 2; ++i) {
    #pragma unroll
    for (int j = 0; j < 8; ++j) {
      int col = wn + j * 16 + (lane & 15);
      int rowb = bm + wm + i * 16 + (lane >> 4) * 4;
      #pragma unroll
      for (int r = 0; r < 4; ++r) {
        int row = rowb + r;
        if (row < M) Cb[(size_t)row * D1 + col] = f2bf(acc[i][j][r]);
      }
    }
  }
}

// ---------------- attention logits per node, layer 1 (wave per node, bf16 h1) ----------------
__global__ __launch_bounds__(256) void k_al1(const u16* __restrict__ h1b,
                                             const float* __restrict__ att_s,
                                             const float* __restrict__ att_d,
                                             float* __restrict__ al_s,
                                             float* __restrict__ al_d) {
  int node = (blockIdx.x * 256 + threadIdx.x) >> 6;
  int lane = threadIdx.x & 63;
  if (node >= N_NODES) return;
  uint2 hv = *(const uint2*)&h1b[(size_t)node * 256 + lane * 4];
  float v0 = bflo(hv.x), v1 = bfhi(hv.x), v2 = bflo(hv.y), v3 = bfhi(hv.y);
  float4 as = *(const float4*)&att_s[lane * 4];
  float4 ad = *(const float4*)&att_d[lane * 4];
  float ps = v0*as.x + v1*as.y + v2*as.z + v3*as.w;
  float pd = v0*ad.x + v1*ad.y + v2*ad.z + v3*ad.w;
  for (int s = 1; s < 8; s <<= 1) {
    ps += __shfl_xor(ps, s, 64);
    pd += __shfl_xor(pd, s, 64);
  }
  if ((lane & 7) == 0) {
    al_s[node * 8 + (lane >> 3)] = ps;
    al_d[node * 8 + (lane >> 3)] = pd;
  }
}

// ---------------- per-edge softmax numerators, layer 1: p1[pos][h] = exp(leaky(...)) ----------------
__global__ __launch_bounds__(256) void k_p1(const int* __restrict__ csr_src,
                                            const int* __restrict__ csr_dst,
                                            const float* __restrict__ al_s,
                                            const float* __restrict__ al_d,
                                            float* __restrict__ p1) {
  int id = blockIdx.x * 256 + threadIdx.x;
  if (id >= EA * 8) return;
  int pos = id >> 3, h = id & 7;
  float e = al_s[csr_src[pos] * 8 + h] + al_d[csr_dst[pos] * 8 + h];
  e = (e > 0.f) ? e : NEG * e;
  p1[id] = __expf(e);
}

// ---------------- layer-1 aggregate + bias + ELU: single pass, p precomputed, 8x unroll ----------------
__global__ __launch_bounds__(256) void k_agg1(const int* __restrict__ rowptr,
                                              const int* __restrict__ csr_src,
                                              const float* __restrict__ p1,
                                              const u16* __restrict__ h1b,
                                              const float* __restrict__ b1,
                                              u32* __restrict__ x2b) {
  int node = (blockIdx.x * 256 + threadIdx.x) >> 6;
  int lane = threadIdx.x & 63;
  if (node >= N_NODES) return;
  int start = rowptr[node], end = rowptr[node + 1];
  int h3 = lane >> 3;
  size_t choff = (size_t)lane * 4;
  float dsum = 0.f;
  float4 acc = make_float4(0.f, 0.f, 0.f, 0.f);
  int idx = start;
  for (; idx + 8 <= end; idx += 8) {
    int s0 = csr_src[idx + 0], s1 = csr_src[idx + 1];
    int s2 = csr_src[idx + 2], s3 = csr_src[idx + 3];
    int s4 = csr_src[idx + 4], s5 = csr_src[idx + 5];
    int s6 = csr_src[idx + 6], s7 = csr_src[idx + 7];
    float pp0 = p1[(idx + 0) * 8 + h3], pp1 = p1[(idx + 1) * 8 + h3];
    float pp2 = p1[(idx + 2) * 8 + h3], pp3 = p1[(idx + 3) * 8 + h3];
    float pp4 = p1[(idx + 4) * 8 + h3], pp5 = p1[(idx + 5) * 8 + h3];
    float pp6 = p1[(idx + 6) * 8 + h3], pp7 = p1[(idx + 7) * 8 + h3];
    uint2 hv0 = *(const uint2*)&h1b[(size_t)s0 * D1 + choff];
    uint2 hv1 = *(const uint2*)&h1b[(size_t)s1 * D1 + choff];
    uint2 hv2 = *(const uint2*)&h1b[(size_t)s2 * D1 + choff];
    uint2 hv3 = *(const uint2*)&h1b[(size_t)s3 * D1 + choff];
    uint2 hv4 = *(const uint2*)&h1b[(size_t)s4 * D1 + choff];
    uint2 hv5 = *(const uint2*)&h1b[(size_t)s5 * D1 + choff];
    uint2 hv6 = *(const uint2*)&h1b[(size_t)s6 * D1 + choff];
    uint2 hv7 = *(const uint2*)&h1b[(size_t)s7 * D1 + choff];
    dsum += ((pp0 + pp1) + (pp2 + pp3)) + ((pp4 + pp5) + (pp6 + pp7));
    acc.x += pp0 * bflo(hv0.x) + pp1 * bflo(hv1.x) + pp2 * bflo(hv2.x) + pp3 * bflo(hv3.x)
           + pp4 * bflo(hv4.x) + pp5 * bflo(hv5.x) + pp6 * bflo(hv6.x) + pp7 * bflo(hv7.x);
    acc.y += pp0 * bfhi(hv0.x) + pp1 * bfhi(hv1.x) + pp2 * bfhi(hv2.x) + pp3 * bfhi(hv3.x)
           + pp4 * bfhi(hv4.x) + pp5 * bfhi(hv5.x) + pp6 * bfhi(hv6.x) + pp7 * bfhi(hv7.x);
    acc.z += pp0 * bflo(hv0.y) + pp1 * bflo(hv1.y) + pp2 * bflo(hv2.y) + pp3 * bflo(hv3.y)
           + pp4 * bflo(hv4.y) + pp5 * bflo(hv5.y) + pp6 * bflo(hv6.y) + pp7 * bflo(hv7.y);
    acc.w += pp0 * bfhi(hv0.y) + pp1 * bfhi(hv1.y) + pp2 * bfhi(hv2.y) + pp3 * bfhi(hv3.y)
           + pp4 * bfhi(hv4.y) + pp5 * bfhi(hv5.y) + pp6 * bfhi(hv6.y) + pp7 * bfhi(hv7.y);
  }
  for (; idx < end; ++idx) {
    int s0 = csr_src[idx];
    float pp0 = p1[idx * 8 + h3];
    uint2 hv0 = *(const uint2*)&h1b[(size_t)s0 * D1 + choff];
    dsum += pp0;
    acc.x += pp0 * bflo(hv0.x);
    acc.y += pp0 * bfhi(hv0.x);
    acc.z += pp0 * bflo(hv0.y);
    acc.w += pp0 * bfhi(hv0.y);
  }
  float inv = 1.f / (dsum + 1e-16f);
  float4 bb = *(const float4*)&b1[lane * 4];
  float vx = acc.x * inv + bb.x; vx = vx > 0.f ? vx : __expf(vx) - 1.f;
  float vy = acc.y * inv + bb.y; vy = vy > 0.f ? vy : __expf(vy) - 1.f;
  float vz = acc.z * inv + bb.z; vz = vz > 0.f ? vz : __expf(vz) - 1.f;
  float vw = acc.w * inv + bb.w; vw = vw > 0.f ? vw : __expf(vw) - 1.f;
  ((uint2*)x2b)[(size_t)node * 64 + lane] = make_uint2(pack2(vx, vy), pack2(vz, vw));
}

// ---------------- GEMM2 (bf16 MFMA): h2b[M,40] (bf16) = x2b[M,256] @ W2T^T ----------------
__global__ __launch_bounds__(256) void k_gemm2_mfma(const u16* __restrict__ A,    // [M,256] bf16
                                                    const u16* __restrict__ W2T,  // [48][256] bf16
                                                    u16* __restrict__ h2b) {      // [M,40] bf16
  __shared__ u16 As[128 * 32];          // 8 KB
  __shared__ u16 Ws[NCLS_P * W2LD];     // 25.3 KB
  const int M = N_NODES;
  int bm = blockIdx.x * 128;
  int t = threadIdx.x;
  int lane = t & 63, wave = t >> 6;
  int wm = wave * 32;

  for (int i = t; i < NCLS_P * (D1 / 2); i += 256) {
    int n = i >> 7, k2 = i & 127;
    *(u32*)&Ws[n * W2LD + k2 * 2] = ((const u32*)W2T)[i];
  }

  int ldrow = wave * 16 + (lane >> 2);
  int ldk   = (lane & 3) * 8;
  int arow0 = bm + ldrow;       if (arow0 >= M) arow0 = M - 1;
  int arow1 = bm + 64 + ldrow;  if (arow1 >= M) arow1 = M - 1;
  u16* asd0 = &As[(wave * 16) * 32];
  u16* asd1 = &As[(64 + wave * 16) * 32];

  int am = wm + (lane & 15);
  int nn = lane & 15;
  int kq = (lane >> 4) * 8;

  f32x4 acc[2][3] = {};

  for (int k0 = 0; k0 < D1; k0 += 32) {
    __builtin_amdgcn_global_load_lds(
        (const __attribute__((address_space(1))) void*)&A[(size_t)arow0 * D1 + k0 + ldk],
        (__attribute__((address_space(3))) void*)asd0, 16, 0, 0);
    __builtin_amdgcn_global_load_lds(
        (const __attribute__((address_space(1))) void*)&A[(size_t)arow1 * D1 + k0 + ldk],
        (__attribute__((address_space(3))) void*)asd1, 16, 0, 0);
    __syncthreads();

    bf16x8 af[2], bfr[3];
    #pragma unroll
    for (int i = 0; i < 2; ++i)
      af[i] = *(const bf16x8*)&As[(am + i * 16) * 32 + kq];
    #pragma unroll
    for (int j = 0; j < 3; ++j)
      bfr[j] = *(const bf16x8*)&Ws[(j * 16 + nn) * W2LD + k0 + kq];
    #pragma unroll
    for (int i = 0; i < 2; ++i)
      #pragma unroll
      for (int j = 0; j < 3; ++j)
        acc[i][j] = __builtin_amdgcn_mfma_f32_16x16x32_bf16(af[i], bfr[j], acc[i][j], 0, 0, 0);
    __syncthreads();
  }

  #pragma unroll
  for (int i = 0; i < 2; ++i) {
    #pragma unroll
    for (int j = 0; j < 3; ++j) {
      int col = j * 16 + (lane & 15);
      if (col >= NCLS) continue;
      int rowb = bm + wm + i * 16 + (lane >> 4) * 4;
      #pragma unroll
      for (int r = 0; r < 4; ++r) {
        int row = rowb + r;
        if (row < M) h2b[(size_t)row * NCLS + col] = f2bf(acc[i][j][r]);
      }
    }
  }
}

// ---------------- al2 on bf16 h2 ----------------
__global__ void k_al2(const u32* __restrict__ h2p, const float* __restrict__ att_s,
                      const float* __restrict__ att_d,
                      float* __restrict__ al_s, float* __restrict__ al_d) {
  int n = blockIdx.x * blockDim.x + threadIdx.x;
  if (n >= N_NODES) return;
  float ps = 0.f, pd = 0.f;
  const u32* hr = &h2p[(size_t)n * (NCLS / 2)];
  for (int c = 0; c < NCLS / 2; ++c) {
    u32 v = hr[c];
    ps += bflo(v) * att_s[2 * c] + bfhi(v) * att_s[2 * c + 1];
    pd += bflo(v) * att_d[2 * c] + bfhi(v) * att_d[2 * c + 1];
  }
  al_s[n] = ps; al_d[n] = pd;
}

// ---------------- per-edge numerators, layer 2 ----------------
__global__ __launch_bounds__(256) void k_p2(const int* __restrict__ csr_src,
                                            const int* __restrict__ csr_dst,
                                            const float* __restrict__ al_s,
                                            const float* __restrict__ al_d,
                                            float* __restrict__ p2) {
  int pos = blockIdx.x * 256 + threadIdx.x;
  if (pos >= EA) return;
  float e = al_s[csr_src[pos]] + al_d[csr_dst[pos]];
  e = (e > 0.f) ? e : NEG * e;
  p2[pos] = __expf(e);
}

// ---------------- layer-2 aggregate + bias: p precomputed, 8x unroll, bf16 h2 ----------------
__global__ __launch_bounds__(256) void k_agg2(const int* __restrict__ rowptr,
                                              const int* __restrict__ csr_src,
                                              const float* __restrict__ p2,
                                              const u32* __restrict__ h2p,
                                              const float* __restrict__ b2,
                                              float* __restrict__ out) {
  int node = (blockIdx.x * 256 + threadIdx.x) >> 6;
  int lane = threadIdx.x & 63;
  if (node >= N_NODES) return;
  int start = rowptr[node], end = rowptr[node + 1];
  int cl = (lane < NCLS / 2) ? lane : 0;
  float dsum = 0.f, accl = 0.f, acch = 0.f;
  int idx = start;
  for (; idx + 8 <= end; idx += 8) {
    int s0 = csr_src[idx + 0], s1 = csr_src[idx + 1];
    int s2 = csr_src[idx + 2], s3 = csr_src[idx + 3];
    int s4 = csr_src[idx + 4], s5 = csr_src[idx + 5];
    int s6 = csr_src[idx + 6], s7 = csr_src[idx + 7];
    float pp0 = p2[idx + 0], pp1 = p2[idx + 1], pp2 = p2[idx + 2], pp3 = p2[idx + 3];
    float pp4 = p2[idx + 4], pp5 = p2[idx + 5], pp6 = p2[idx + 6], pp7 = p2[idx + 7];
    u32 g0 = h2p[(size_t)s0 * (NCLS / 2) + cl];
    u32 g1 = h2p[(size_t)s1 * (NCLS / 2) + cl];
    u32 g2 = h2p[(size_t)s2 * (NCLS / 2) + cl];
    u32 g3 = h2p[(size_t)s3 * (NCLS / 2) + cl];
    u32 g4 = h2p[(size_t)s4 * (NCLS / 2) + cl];
    u32 g5 = h2p[(size_t)s5 * (NCLS / 2) + cl];
    u32 g6 = h2p[(size_t)s6 * (NCLS / 2) + cl];
    u32 g7 = h2p[(size_t)s7 * (NCLS / 2) + cl];
    dsum += ((pp0 + pp1) + (pp2 + pp3)) + ((pp4 + pp5) + (pp6 + pp7));
    accl += pp0 * bflo(g0) + pp1 * bflo(g1) + pp2 * bflo(g2) + pp3 * bflo(g3)
          + pp4 * bflo(g4) + pp5 * bflo(g5) + pp6 * bflo(g6) + pp7 * bflo(g7);
    acch += pp0 * bfhi(g0) + pp1 * bfhi(g1) + pp2 * bfhi(g2) + pp3 * bfhi(g3)
          + pp4 * bfhi(g4) + pp5 * bfhi(g5) + pp6 * bfhi(g6) + pp7 * bfhi(g7);
  }
  for (; idx < end; ++idx) {
    int s0 = csr_src[idx];
    float pp0 = p2[idx];
    u32 g0 = h2p[(size_t)s0 * (NCLS / 2) + cl];
    dsum += pp0;
    accl += pp0 * bflo(g0);
    acch += pp0 * bfhi(g0);
  }
  float inv = 1.f / (dsum + 1e-16f);
  if (lane < NCLS / 2) {
    out[(size_t)node * NCLS + 2 * lane]     = accl * inv + b2[2 * lane];
    out[(size_t)node * NCLS + 2 * lane + 1] = acch * inv + b2[2 * lane + 1];
  }
}

extern "C" void kernel_launch(void* const* d_in, const int* in_sizes, int n_in,
                              void* d_out, int out_size, void* d_ws, size_t ws_size,
                              hipStream_t stream) {
  const float* x   = (const float*)d_in[0];
  const int*   ei  = (const int*)d_in[1];
  const float* W1  = (const float*)d_in[2];
  const float* as1 = (const float*)d_in[3];
  const float* ad1 = (const float*)d_in[4];
  const float* b1  = (const float*)d_in[5];
  const float* W2  = (const float*)d_in[6];
  const float* as2 = (const float*)d_in[7];
  const float* ad2 = (const float*)d_in[8];
  const float* b2  = (const float*)d_in[9];
  float* out = (float*)d_out;

  // workspace carve-up (~100 MB)
  char* p = (char*)d_ws;
  auto alloc = [&](size_t bytes) { char* r = p; p += (bytes + 15) & ~size_t(15); return r; };
  u16*  h1b    = (u16*)alloc((size_t)N_NODES * D1 * 2);     // 25.6 MB bf16
  u32*  x2b    = (u32*)alloc((size_t)N_NODES * D1 * 2);     // 25.6 MB bf16 pairs
  u16*  h2b    = (u16*)alloc((size_t)N_NODES * NCLS * 2);   // 4 MB bf16
  float* p1    = (float*)alloc((size_t)EA * 8 * 4);         // 27.2 MB
  float* p2    = (float*)alloc((size_t)EA * 4);             // 3.4 MB
  float* al_s1 = (float*)alloc((size_t)N_NODES * 8 * 4);
  float* al_d1 = (float*)alloc((size_t)N_NODES * 8 * 4);
  float* al_s2 = (float*)alloc((size_t)N_NODES * 4);
  float* al_d2 = (float*)alloc((size_t)N_NODES * 4);
  int* deg     = (int*)alloc((size_t)N_NODES * 4);
  int* rowptr  = (int*)alloc((size_t)(N_NODES + 1) * 4);
  int* wofs    = (int*)alloc((size_t)N_NODES * 4);
  int* partial = (int*)alloc(128 * 4);
  int* csr_src = (int*)alloc((size_t)EA * 4);
  int* csr_dst = (int*)alloc((size_t)EA * 4);
  u16* w1t     = (u16*)alloc((size_t)D1 * IN_CH * 2);
  u16* w2t     = (u16*)alloc((size_t)NCLS_P * D1 * 2);

  const int NB = (N_NODES + 511) / 512;  // 98

  hipMemsetAsync(deg, 0, (size_t)N_NODES * 4, stream);
  k_hist<<<(EA + 255) / 256, 256, 0, stream>>>(ei, deg);
  k_scan_partial<<<NB, 512, 0, stream>>>(deg, partial);
  k_scan_top<<<1, 64, 0, stream>>>(partial, NB);
  k_scan_final<<<NB, 512, 0, stream>>>(deg, partial, rowptr, wofs);
  k_scatter<<<(EA + 255) / 256, 256, 0, stream>>>(ei, wofs, csr_src, csr_dst);

  const int WTOT = D1 * IN_CH + NCLS_P * D1;
  k_cast_w<<<(WTOT + 255) / 256, 256, 0, stream>>>(W1, W2, w1t, w2t);

  k_gemm1_fused<<<(N_NODES + 63) / 64, 256, 0, stream>>>(x, w1t, h1b);

  k_al1<<<(N_NODES + 3) / 4, 256, 0, stream>>>(h1b, as1, ad1, al_s1, al_d1);
  k_p1<<<(EA * 8 + 255) / 256, 256, 0, stream>>>(csr_src, csr_dst, al_s1, al_d1, p1);
  k_agg1<<<(N_NODES + 3) / 4, 256, 0, stream>>>(rowptr, csr_src, p1, h1b, b1, x2b);

  k_gemm2_mfma<<<(N_NODES + 127) / 128, 256, 0, stream>>>((const u16*)x2b, w2t, h2b);
  k_al2<<<(N_NODES + 255) / 256, 256, 0, stream>>>((const u32*)h2b, as2, ad2, al_s2, al_d2);
  k_p2<<<(EA + 255) / 256, 256, 0, stream>>>(csr_src, csr_dst, al_s2, al_d2, p2);
  k_agg2<<<(N_NODES + 3) / 4, 256, 0, stream>>>(rowptr, csr_src, p2, (const u32*)h2b, b2, out);
}